// Round 2
// baseline (1680.206 us; speedup 1.0000x reference)
//
#include <hip/hip_runtime.h>

// ---------------------------------------------------------------------------
// MLA prefill (B=4, S=2048, D=768, H=8, q_rank=kv_rank=rope=64, nope=32, v=96)
// Round 2: dtype-agnostic (runtime-detected fp32 vs bf16 inputs/outputs),
// fp32 vector pipeline. Flash attention with online softmax, no mask.
// ---------------------------------------------------------------------------

#define DEV static __device__ __forceinline__

DEV float bf2f(unsigned int u) {
    union { float f; unsigned int i; } x; x.i = u << 16; return x.f;
}
DEV unsigned short f2bf(float f) {
    union { float f; unsigned int u; } x; x.f = f;
    unsigned int u = x.u;
    return (unsigned short)((u + 0x7fffu + ((u >> 16) & 1u)) >> 16);
}
DEV float ldin(const void* p, size_t i, int isbf) {
    return isbf ? bf2f(((const unsigned short*)p)[i]) : ((const float*)p)[i];
}

constexpr int   TOK   = 4 * 2048;                         // 8192 tokens
constexpr float EPSF  = 1e-6f;
constexpr float SCALE = 0.10206207261596575f;             // 96^-0.5
constexpr float L2_10000_OVER_32 = 0.4152410118609203f;   // log2(10000)/32

// workspace layout (float offsets)
constexpr size_t OFF_WOT   = 0;                               // woT  [768][768]
constexpr size_t OFF_WKVAT = OFF_WOT   + 768 * 768;           // wkv_aT [768][128]
constexpr size_t OFF_WQAT  = OFF_WKVAT + 768 * 128;           // wq_aT  [768][64]
constexpr size_t OFF_WQBT  = OFF_WQAT  + 768 * 64;            // wq_bT  [64][768]
constexpr size_t OFF_QAF   = OFF_WQBT  + 64 * 768;            // q_absorb [8][32][64]
constexpr size_t OFF_OAT   = OFF_QAF   + 8 * 32 * 64;         // out_absorbT [8][64][96]
constexpr size_t OFF_QLN   = OFF_OAT   + 8 * 64 * 96;         // q_a_ln_w [64] fp32
constexpr size_t OFF_KVLN  = OFF_QLN   + 64;                  // kv_a_ln_w [64]
constexpr size_t OFF_NW    = OFF_KVLN  + 64;                  // norm_w [768]
constexpr size_t OFF_FLAG  = OFF_NW    + 768;                 // dtype flag (int)
constexpr size_t OFF_KP    = OFF_FLAG  + 16;                  // K' [4][2048][128]
constexpr size_t OFF_QP    = OFF_KP    + (size_t)TOK * 128;   // Q' [4][8][2048][128]
constexpr size_t OFF_CTXF  = OFF_QP    + (size_t)TOK * 8 * 128; // ctx_flat [8192][768]

// ---------------------------------------------------------------------------
// det: norm_w is ones. fp32 ones -> word0 = 0x3F800000 (low16 == 0);
//      bf16 ones -> word0 = 0x3F803F80 (low16 != 0).
// ---------------------------------------------------------------------------
__global__ void det_k(const unsigned int* __restrict__ nw_u, int* __restrict__ flag) {
    *flag = ((nw_u[0] & 0xffffu) != 0u) ? 1 : 0;
}

// ---------------------------------------------------------------------------
// prep: transpose weights (either dtype) -> fp32 into ws
// ---------------------------------------------------------------------------
__global__ __launch_bounds__(256) void prep_k(
    const void* __restrict__ wq_a, const void* __restrict__ q_ln,
    const void* __restrict__ wq_b, const void* __restrict__ wkv_a,
    const void* __restrict__ kv_ln, const void* __restrict__ wkv_b,
    const void* __restrict__ wo, const void* __restrict__ nw,
    float* __restrict__ ws)
{
    const int isbf = ((const int*)ws)[OFF_FLAG];
    int i = blockIdx.x * 256 + threadIdx.x;
    int y = blockIdx.y;
    if (y == 0) {        // woT[k*768+o] = wo[o][k]
        if (i < 768 * 768) { int k = i / 768, o = i - k * 768; ws[OFF_WOT + i] = ldin(wo, (size_t)o * 768 + k, isbf); }
    } else if (y == 1) { // wkv_aT[k*128+o] = wkv_a[o][k]
        if (i < 768 * 128) { int k = i >> 7, o = i & 127; ws[OFF_WKVAT + i] = ldin(wkv_a, (size_t)o * 768 + k, isbf); }
    } else if (y == 2) { // wq_aT[k*64+o] = wq_a[o][k]
        if (i < 768 * 64) { int k = i >> 6, o = i & 63; ws[OFF_WQAT + i] = ldin(wq_a, (size_t)o * 768 + k, isbf); }
    } else if (y == 3) { // wq_bT[k*768+o] = wq_b[o][k]
        if (i < 64 * 768) { int k = i / 768, o = i - k * 768; ws[OFF_WQBT + i] = ldin(wq_b, (size_t)o * 64 + k, isbf); }
    } else if (y == 4) { // q_absorb [h][d][r]
        if (i < 8 * 32 * 64) { int h = i >> 11; ws[OFF_QAF + i] = ldin(wkv_b, (size_t)h * 8192 + (i & 2047), isbf); }
    } else if (y == 5) { // out_absorbT [h][r][v] = wkv_b[h*128+32+v][r]
        if (i < 8 * 64 * 96) {
            int h = i / 6144, rem = i - h * 6144;
            int r = rem / 96, v = rem - r * 96;
            ws[OFF_OAT + i] = ldin(wkv_b, (size_t)h * 8192 + 2048 + v * 64 + r, isbf);
        }
    } else {             // norm vectors
        if (i < 64)                  ws[OFF_QLN + i]        = ldin(q_ln, i, isbf);
        else if (i < 128)            ws[OFF_KVLN + i - 64]  = ldin(kv_ln, i - 64, isbf);
        else if (i < 128 + 768)      ws[OFF_NW + i - 128]   = ldin(nw, i - 128, isbf);
    }
}

// ---------------------------------------------------------------------------
// k1: ckv = src @ wkv_a^T ; c_lat = rmsnorm(ckv[:64])*w ; k_pe = rope(ckv[64:])
//     -> K'[token][128] fp32.  32 tokens/block, 256 threads (o=tid&127).
// ---------------------------------------------------------------------------
__global__ __launch_bounds__(256) void k1_ckv(
    const void* __restrict__ src, const float* __restrict__ ws, float* __restrict__ Kp)
{
    const float* wkvaT = ws + OFF_WKVAT;
    const float* kvln  = ws + OFF_KVLN;
    const int isbf = ((const int*)ws)[OFF_FLAG];
    __shared__ float slds[32][68];
    __shared__ float ckv[32][132];
    int j = threadIdx.x;
    int t0 = blockIdx.x * 32;
    int o = j & 127, tg = j >> 7;
    float acc[16];
#pragma unroll
    for (int i = 0; i < 16; ++i) acc[i] = 0.f;

    for (int k0 = 0; k0 < 768; k0 += 64) {
        {   // stage 32x64 chunk of src into LDS (fp32)
            int tt = j >> 3, kk = (j & 7) * 8;
            size_t off = (size_t)(t0 + tt) * 768 + k0 + kk;
            float* d = &slds[tt][kk];
            if (isbf) {
                uint4 u = *(const uint4*)((const unsigned short*)src + off);
                d[0] = bf2f(u.x & 0xffff); d[1] = bf2f(u.x >> 16);
                d[2] = bf2f(u.y & 0xffff); d[3] = bf2f(u.y >> 16);
                d[4] = bf2f(u.z & 0xffff); d[5] = bf2f(u.z >> 16);
                d[6] = bf2f(u.w & 0xffff); d[7] = bf2f(u.w >> 16);
            } else {
                const float4* p = (const float4*)((const float*)src + off);
                *(float4*)&d[0] = p[0];
                *(float4*)&d[4] = p[1];
            }
        }
        __syncthreads();
#pragma unroll 1
        for (int kk = 0; kk < 64; kk += 4) {
            float w0 = wkvaT[(k0 + kk) * 128 + o];
            float w1 = wkvaT[(k0 + kk + 1) * 128 + o];
            float w2 = wkvaT[(k0 + kk + 2) * 128 + o];
            float w3 = wkvaT[(k0 + kk + 3) * 128 + o];
#pragma unroll
            for (int i = 0; i < 16; ++i) {
                float4 s4 = *(const float4*)&slds[tg * 16 + i][kk];
                acc[i] += s4.x * w0 + s4.y * w1 + s4.z * w2 + s4.w * w3;
            }
        }
        __syncthreads();
    }
#pragma unroll
    for (int i = 0; i < 16; ++i) ckv[tg * 16 + i][o] = acc[i];
    __syncthreads();

    {   // epilogue: tt = token in tile, l = 8 lanes per token
        int tt = j >> 3, l = j & 7;
        float ss = 0.f;
#pragma unroll
        for (int i = 0; i < 8; ++i) { float v = ckv[tt][l * 8 + i]; ss += v * v; }
        ss += __shfl_xor(ss, 1); ss += __shfl_xor(ss, 2); ss += __shfl_xor(ss, 4);
        float rs = rsqrtf(ss * (1.f / 64.f) + EPSF);
        size_t base = (size_t)(t0 + tt) * 128;
#pragma unroll
        for (int i = 0; i < 8; ++i) {
            int o2 = l * 8 + i;
            float cl = ckv[tt][o2] * rs;
            if (isbf) cl = bf2f(f2bf(cl));   // reference: .astype(bf16) before *w
            Kp[base + o2] = cl * kvln[o2];
        }
        int pos = (t0 + tt) & 2047;
#pragma unroll
        for (int i = 0; i < 4; ++i) {
            int p = l * 4 + i;
            float inv = exp2f(-(float)p * L2_10000_OVER_32);
            float ang = (float)pos * inv;
            float sn = sinf(ang), cs = cosf(ang);
            float e = ckv[tt][64 + 2 * p], od = ckv[tt][64 + 2 * p + 1];
            Kp[base + 64 + p] = e * cs - od * sn;
            Kp[base + 96 + p] = od * cs + e * sn;
        }
    }
}

// ---------------------------------------------------------------------------
// k2: q = rmsnorm(src@wq_a^T)@wq_b^T ; per head: q_lat = q_nope@q_absorb,
//     q_pe = rope(q_pe). Store Q'[b][h][s][128] * SCALE.  8 tokens/block.
// ---------------------------------------------------------------------------
__global__ __launch_bounds__(256) void k2_q(
    const void* __restrict__ src, const float* __restrict__ ws, float* __restrict__ Qp)
{
    const float* wqaT = ws + OFF_WQAT;
    const float* wqbT = ws + OFF_WQBT;
    const float* qaF  = ws + OFF_QAF;
    const float* qln  = ws + OFF_QLN;
    const int isbf = ((const int*)ws)[OFF_FLAG];
    __shared__ float slds[8][68];
    __shared__ float tlds[8][68];
    __shared__ float qlds[8][768];
    int j = threadIdx.x;
    int t0 = blockIdx.x * 8;

    {   // stage A: tmp = src @ wq_a^T  (o = j&63, 4 token groups x 2 tokens)
        int o = j & 63, tg = j >> 6;
        float a0 = 0.f, a1 = 0.f;
        for (int k0 = 0; k0 < 768; k0 += 64) {
            {
                int tt = j >> 5, kk = (j & 31) * 2;
                size_t off = (size_t)(t0 + tt) * 768 + k0 + kk;
                if (isbf) {
                    unsigned int u = *(const unsigned int*)((const unsigned short*)src + off);
                    slds[tt][kk] = bf2f(u & 0xffff); slds[tt][kk + 1] = bf2f(u >> 16);
                } else {
                    const float* p = (const float*)src + off;
                    slds[tt][kk] = p[0]; slds[tt][kk + 1] = p[1];
                }
            }
            __syncthreads();
#pragma unroll 1
            for (int kk = 0; kk < 64; kk += 4) {
                float w0 = wqaT[(k0 + kk) * 64 + o], w1 = wqaT[(k0 + kk + 1) * 64 + o];
                float w2 = wqaT[(k0 + kk + 2) * 64 + o], w3 = wqaT[(k0 + kk + 3) * 64 + o];
                float4 s0 = *(const float4*)&slds[tg * 2][kk];
                float4 s1 = *(const float4*)&slds[tg * 2 + 1][kk];
                a0 += s0.x * w0 + s0.y * w1 + s0.z * w2 + s0.w * w3;
                a1 += s1.x * w0 + s1.y * w1 + s1.z * w2 + s1.w * w3;
            }
            __syncthreads();
        }
        tlds[tg * 2][o] = a0; tlds[tg * 2 + 1][o] = a1;
    }
    __syncthreads();
    {   // rms norm rows of tlds (width 64)
        int tt = j >> 5, l = j & 31;
        float v0 = tlds[tt][l * 2], v1 = tlds[tt][l * 2 + 1];
        float ss = v0 * v0 + v1 * v1;
        ss += __shfl_xor(ss, 1); ss += __shfl_xor(ss, 2); ss += __shfl_xor(ss, 4);
        ss += __shfl_xor(ss, 8); ss += __shfl_xor(ss, 16);
        float rs = rsqrtf(ss * (1.f / 64.f) + EPSF);
        float n0 = v0 * rs, n1 = v1 * rs;
        if (isbf) { n0 = bf2f(f2bf(n0)); n1 = bf2f(f2bf(n1)); }
        tlds[tt][l * 2]     = n0 * qln[l * 2];
        tlds[tt][l * 2 + 1] = n1 * qln[l * 2 + 1];
    }
    __syncthreads();
    {   // stage B: q[8][768] = tmpn @ wq_b^T ; each thread 3 cols x 8 tokens
        float qa[8][3];
#pragma unroll
        for (int i = 0; i < 8; ++i) { qa[i][0] = 0.f; qa[i][1] = 0.f; qa[i][2] = 0.f; }
#pragma unroll 1
        for (int k = 0; k < 64; k += 4) {
            float w[4][3];
#pragma unroll
            for (int kk = 0; kk < 4; ++kk) {
                const float* wp = wqbT + (size_t)(k + kk) * 768 + j;
                w[kk][0] = wp[0]; w[kk][1] = wp[256]; w[kk][2] = wp[512];
            }
#pragma unroll
            for (int i = 0; i < 8; ++i) {
                float4 t4 = *(const float4*)&tlds[i][k];
                qa[i][0] += t4.x * w[0][0] + t4.y * w[1][0] + t4.z * w[2][0] + t4.w * w[3][0];
                qa[i][1] += t4.x * w[0][1] + t4.y * w[1][1] + t4.z * w[2][1] + t4.w * w[3][1];
                qa[i][2] += t4.x * w[0][2] + t4.y * w[1][2] + t4.z * w[2][2] + t4.w * w[3][2];
            }
        }
#pragma unroll
        for (int i = 0; i < 8; ++i) {
            qlds[i][j] = qa[i][0]; qlds[i][j + 256] = qa[i][1]; qlds[i][j + 512] = qa[i][2];
        }
    }
    __syncthreads();
    {   // stage C: per (token, head): q_lat + roped q_pe -> Q'
        int wv = j >> 6, lane = j & 63;
        for (int u = wv * 16; u < wv * 16 + 16; ++u) {
            int tt = u >> 3, h = u & 7;
            int qb = h * 96;
            float acc = 0.f;
#pragma unroll 4
            for (int d = 0; d < 32; ++d) acc += qlds[tt][qb + d] * qaF[(h * 32 + d) * 64 + lane];
            int token = t0 + tt, pos = token & 2047;
            size_t qoff = ((size_t)((token >> 11) * 8 + h) * 2048 + pos) * 128;
            Qp[qoff + lane] = acc * SCALE;
            if (lane < 32) {
                int p = lane;
                float e = qlds[tt][qb + 32 + 2 * p], od = qlds[tt][qb + 32 + 2 * p + 1];
                float inv = exp2f(-(float)p * L2_10000_OVER_32);
                float ang = (float)pos * inv;
                float sn = sinf(ang), cs = cosf(ang);
                Qp[qoff + 64 + p] = (e * cs - od * sn) * SCALE;
                Qp[qoff + 96 + p] = (od * cs + e * sn) * SCALE;
            }
        }
    }
}

// ---------------------------------------------------------------------------
// k3: flash attention. grid (64,8,4): 32 queries/block, K tiles of 64.
// ---------------------------------------------------------------------------
__global__ __launch_bounds__(256) void k3_attn(
    const float* __restrict__ Qp, const float* __restrict__ Kp,
    const float* __restrict__ oaT, float* __restrict__ ctxf)
{
    __shared__ float Qs[32][132];
    __shared__ float Ks[64][132];
    __shared__ float Ps[32][68];
    int j = threadIdx.x;
    int b = blockIdx.z, h = blockIdx.y, q0g = blockIdx.x * 32;

    {   // load Q tile
        int q = j >> 3, k0 = (j & 7) * 16;
        const float* p = Qp + ((size_t)(b * 8 + h) * 2048 + q0g + q) * 128 + k0;
        *(float4*)&Qs[q][k0]      = ((const float4*)p)[0];
        *(float4*)&Qs[q][k0 + 4]  = ((const float4*)p)[1];
        *(float4*)&Qs[q][k0 + 8]  = ((const float4*)p)[2];
        *(float4*)&Qs[q][k0 + 12] = ((const float4*)p)[3];
    }
    int qi = j >> 4, ti = j & 15, q0 = qi * 2;
    float m0 = -1e30f, m1 = -1e30f, l0 = 0.f, l1 = 0.f;
    float O[2][4];
#pragma unroll
    for (int a = 0; a < 2; ++a) { O[a][0] = 0.f; O[a][1] = 0.f; O[a][2] = 0.f; O[a][3] = 0.f; }
    const float* kbase = Kp + (size_t)b * 2048 * 128;

    for (int it = 0; it < 32; ++it) {
        __syncthreads();
        {   // load K tile (64 x 128)
            int t = j >> 2, k0 = (j & 3) * 32;
            const float* p = kbase + (size_t)(it * 64 + t) * 128 + k0;
#pragma unroll
            for (int c = 0; c < 8; ++c) *(float4*)&Ks[t][k0 + c * 4] = ((const float4*)p)[c];
        }
        __syncthreads();
        float sc[2][4];
#pragma unroll
        for (int a = 0; a < 2; ++a) { sc[a][0] = 0.f; sc[a][1] = 0.f; sc[a][2] = 0.f; sc[a][3] = 0.f; }
#pragma unroll 2
        for (int k = 0; k < 128; k += 4) {
            float4 qa = *(const float4*)&Qs[q0][k];
            float4 qb = *(const float4*)&Qs[q0 + 1][k];
#pragma unroll
            for (int c = 0; c < 4; ++c) {
                float4 kv = *(const float4*)&Ks[ti + c * 16][k];
                sc[0][c] += qa.x * kv.x + qa.y * kv.y + qa.z * kv.z + qa.w * kv.w;
                sc[1][c] += qb.x * kv.x + qb.y * kv.y + qb.z * kv.z + qb.w * kv.w;
            }
        }
        float al0, al1;
        {
            float mt = fmaxf(fmaxf(sc[0][0], sc[0][1]), fmaxf(sc[0][2], sc[0][3]));
            mt = fmaxf(mt, __shfl_xor(mt, 1)); mt = fmaxf(mt, __shfl_xor(mt, 2));
            mt = fmaxf(mt, __shfl_xor(mt, 4)); mt = fmaxf(mt, __shfl_xor(mt, 8));
            float mn = fmaxf(m0, mt);
            al0 = __expf(m0 - mn);
            float rsum = 0.f;
#pragma unroll
            for (int c = 0; c < 4; ++c) { float p = __expf(sc[0][c] - mn); sc[0][c] = p; rsum += p; }
            rsum += __shfl_xor(rsum, 1); rsum += __shfl_xor(rsum, 2);
            rsum += __shfl_xor(rsum, 4); rsum += __shfl_xor(rsum, 8);
            l0 = l0 * al0 + rsum; m0 = mn;
        }
        {
            float mt = fmaxf(fmaxf(sc[1][0], sc[1][1]), fmaxf(sc[1][2], sc[1][3]));
            mt = fmaxf(mt, __shfl_xor(mt, 1)); mt = fmaxf(mt, __shfl_xor(mt, 2));
            mt = fmaxf(mt, __shfl_xor(mt, 4)); mt = fmaxf(mt, __shfl_xor(mt, 8));
            float mn = fmaxf(m1, mt);
            al1 = __expf(m1 - mn);
            float rsum = 0.f;
#pragma unroll
            for (int c = 0; c < 4; ++c) { float p = __expf(sc[1][c] - mn); sc[1][c] = p; rsum += p; }
            rsum += __shfl_xor(rsum, 1); rsum += __shfl_xor(rsum, 2);
            rsum += __shfl_xor(rsum, 4); rsum += __shfl_xor(rsum, 8);
            l1 = l1 * al1 + rsum; m1 = mn;
        }
#pragma unroll
        for (int c = 0; c < 4; ++c) { Ps[q0][ti + c * 16] = sc[0][c]; Ps[q0 + 1][ti + c * 16] = sc[1][c]; }
#pragma unroll
        for (int d = 0; d < 4; ++d) { O[0][d] *= al0; O[1][d] *= al1; }
        __syncthreads();
        int d0 = ti * 4;
#pragma unroll 4
        for (int t = 0; t < 64; ++t) {
            float pa = Ps[q0][t], pb = Ps[q0 + 1][t];
            float4 vv = *(const float4*)&Ks[t][d0];
            O[0][0] += pa * vv.x; O[0][1] += pa * vv.y; O[0][2] += pa * vv.z; O[0][3] += pa * vv.w;
            O[1][0] += pb * vv.x; O[1][1] += pb * vv.y; O[1][2] += pb * vv.z; O[1][3] += pb * vv.w;
        }
    }
    __syncthreads();
    {
        float il0 = 1.f / l0, il1 = 1.f / l1;
        int d0 = ti * 4;
#pragma unroll
        for (int d = 0; d < 4; ++d) { Ps[q0][d0 + d] = O[0][d] * il0; Ps[q0 + 1][d0 + d] = O[1][d] * il1; }
    }
    __syncthreads();
    {   // fused out_absorb: ctx2[tt][v] = sum_r O[tt][r]*oaT[h][r][v]
#pragma unroll 1
        for (int rep = 0; rep < 12; ++rep) {
            int idx = rep * 256 + j;
            int tt = idx / 96, v = idx - tt * 96;
            float acc = 0.f;
#pragma unroll 4
            for (int r = 0; r < 64; ++r) acc += Ps[tt][r] * oaT[h * 6144 + r * 96 + v];
            ctxf[(size_t)(b * 2048 + q0g + tt) * 768 + h * 96 + v] = acc;
        }
    }
}

// ---------------------------------------------------------------------------
// k5: attn_out = ctx_flat @ wo^T ; y = src + attn_out ; out = rmsnorm(y)*w
// ---------------------------------------------------------------------------
__global__ __launch_bounds__(256) void k5_out(
    const void* __restrict__ src, const float* __restrict__ ws,
    const float* __restrict__ ctxf, void* __restrict__ out)
{
    const float* woT = ws + OFF_WOT;
    const float* nw  = ws + OFF_NW;
    const int isbf = ((const int*)ws)[OFF_FLAG];
    __shared__ float clds[16][132];
    __shared__ float ylds[16][772];
    int j = threadIdx.x;
    int t0 = blockIdx.x * 16;
    float acc[16][3];
#pragma unroll
    for (int tt = 0; tt < 16; ++tt) { acc[tt][0] = 0.f; acc[tt][1] = 0.f; acc[tt][2] = 0.f; }

    for (int k0 = 0; k0 < 768; k0 += 128) {
        {
            int tt = j >> 4, kk = (j & 15) * 8;
            const float* p = ctxf + (size_t)(t0 + tt) * 768 + k0 + kk;
            *(float4*)&clds[tt][kk]     = ((const float4*)p)[0];
            *(float4*)&clds[tt][kk + 4] = ((const float4*)p)[1];
        }
        __syncthreads();
#pragma unroll 1
        for (int k = 0; k < 128; k += 4) {
            float w[4][3];
#pragma unroll
            for (int kk = 0; kk < 4; ++kk) {
                const float* wp = woT + (size_t)(k0 + k + kk) * 768 + j;
                w[kk][0] = wp[0]; w[kk][1] = wp[256]; w[kk][2] = wp[512];
            }
#pragma unroll
            for (int tt = 0; tt < 16; ++tt) {
                float4 c4 = *(const float4*)&clds[tt][k];
                acc[tt][0] += c4.x * w[0][0] + c4.y * w[1][0] + c4.z * w[2][0] + c4.w * w[3][0];
                acc[tt][1] += c4.x * w[0][1] + c4.y * w[1][1] + c4.z * w[2][1] + c4.w * w[3][1];
                acc[tt][2] += c4.x * w[0][2] + c4.y * w[1][2] + c4.z * w[2][2] + c4.w * w[3][2];
            }
        }
        __syncthreads();
    }
#pragma unroll
    for (int tt = 0; tt < 16; ++tt) {
        size_t base = (size_t)(t0 + tt) * 768;
        ylds[tt][j]       = acc[tt][0] + ldin(src, base + j, isbf);
        ylds[tt][j + 256] = acc[tt][1] + ldin(src, base + j + 256, isbf);
        ylds[tt][j + 512] = acc[tt][2] + ldin(src, base + j + 512, isbf);
    }
    __syncthreads();
    {
        int tt = j >> 4, l = j & 15;
        float ss = 0.f;
#pragma unroll 1
        for (int i = 0; i < 48; ++i) { float v = ylds[tt][l + 16 * i]; ss += v * v; }
        ss += __shfl_xor(ss, 1); ss += __shfl_xor(ss, 2); ss += __shfl_xor(ss, 4); ss += __shfl_xor(ss, 8);
        float rs = rsqrtf(ss * (1.f / 768.f) + EPSF);
        size_t base = (size_t)(t0 + tt) * 768;
#pragma unroll 1
        for (int i = 0; i < 48; ++i) {
            int o = l + 16 * i;
            float yv = ylds[tt][o] * rs;
            if (isbf) {
                yv = bf2f(f2bf(yv));   // reference casts to x.dtype before *w
                ((unsigned short*)out)[base + o] = f2bf(yv * nw[o]);
            } else {
                ((float*)out)[base + o] = yv * nw[o];
            }
        }
    }
}

// ---------------------------------------------------------------------------
extern "C" void kernel_launch(void* const* d_in, const int* in_sizes, int n_in,
                              void* d_out, int out_size, void* d_ws, size_t ws_size,
                              hipStream_t stream)
{
    const void* src   = d_in[0];
    const void* wq_a  = d_in[1];
    const void* q_ln  = d_in[2];
    const void* wq_b  = d_in[3];
    const void* wkv_a = d_in[4];
    const void* kv_ln = d_in[5];
    const void* wkv_b = d_in[6];
    const void* wo    = d_in[7];
    const void* nw    = d_in[8];
    float* ws = (float*)d_ws;

    det_k<<<dim3(1), dim3(1), 0, stream>>>((const unsigned int*)nw, (int*)ws + OFF_FLAG);
    prep_k<<<dim3(2304, 7), dim3(256), 0, stream>>>(wq_a, q_ln, wq_b, wkv_a, kv_ln, wkv_b, wo, nw, ws);
    k1_ckv<<<dim3(TOK / 32), dim3(256), 0, stream>>>(src, ws, ws + OFF_KP);
    k2_q<<<dim3(TOK / 8), dim3(256), 0, stream>>>(src, ws, ws + OFF_QP);
    k3_attn<<<dim3(64, 8, 4), dim3(256), 0, stream>>>(ws + OFF_QP, ws + OFF_KP,
                                                      ws + OFF_OAT, ws + OFF_CTXF);
    k5_out<<<dim3(TOK / 16), dim3(256), 0, stream>>>(src, ws, ws + OFF_CTXF, d_out);
}

// Round 3
// 615.192 us; speedup vs baseline: 2.7312x; 2.7312x over previous
//
#include <hip/hip_runtime.h>

// ---------------------------------------------------------------------------
// MLA prefill (B=4, S=2048, D=768, H=8, q_rank=kv_rank=rope=64, nope=32, v=96)
// Round 3: MFMA (16x16x32 bf16) flash attention; projections stay fp32 vector.
// ---------------------------------------------------------------------------

#define DEV static __device__ __forceinline__
typedef unsigned short ushort_t;
typedef __attribute__((ext_vector_type(8))) short bf8_t;
typedef __attribute__((ext_vector_type(4))) float f4_t;

DEV float bf2f(unsigned int u) {
    union { float f; unsigned int i; } x; x.i = u << 16; return x.f;
}
DEV ushort_t f2bf(float f) {
    union { float f; unsigned int u; } x; x.f = f;
    unsigned int u = x.u;
    return (ushort_t)((u + 0x7fffu + ((u >> 16) & 1u)) >> 16);
}
DEV float ldin(const void* p, size_t i, int isbf) {
    return isbf ? bf2f(((const ushort_t*)p)[i]) : ((const float*)p)[i];
}

constexpr int   TOK   = 4 * 2048;                         // 8192 tokens
constexpr float EPSF  = 1e-6f;
constexpr float SCALE = 0.10206207261596575f;             // 96^-0.5
constexpr float L2_10000_OVER_32 = 0.4152410118609203f;   // log2(10000)/32

// workspace layout (float offsets)
constexpr size_t OFF_WOT   = 0;                 // woT  [768][768]
constexpr size_t OFF_WKVAT = 589824;            // wkv_aT [768][128]
constexpr size_t OFF_WQAT  = 688128;            // wq_aT  [768][64]
constexpr size_t OFF_WQBT  = 737280;            // wq_bT  [64][768]
constexpr size_t OFF_QAF   = 786432;            // q_absorb [8][32][64]
constexpr size_t OFF_OAT   = 802816;            // out_absorbT [8][r=64][v=96] fp32
constexpr size_t OFF_QLN   = 851968;
constexpr size_t OFF_KVLN  = 852032;
constexpr size_t OFF_NW    = 852096;
constexpr size_t OFF_FLAG  = 852864;
constexpr size_t OFF_CTXF  = 852880;            // ctx_flat [8192][768] fp32
constexpr size_t OFF_KBF   = 7144336;           // K' bf16 [4][2048][128]
constexpr size_t OFF_VTB   = 7668624;           // V^T bf16 [4][64][2048]
constexpr size_t OFF_QBF   = 7930768;           // Q' bf16 [4][8][2048][128]

// ---------------------------------------------------------------------------
__global__ void det_k(const unsigned int* __restrict__ nw_u, int* __restrict__ flag) {
    *flag = ((nw_u[0] & 0xffffu) != 0u) ? 1 : 0;
}

// ---------------------------------------------------------------------------
__global__ __launch_bounds__(256) void prep_k(
    const void* __restrict__ wq_a, const void* __restrict__ q_ln,
    const void* __restrict__ wq_b, const void* __restrict__ wkv_a,
    const void* __restrict__ kv_ln, const void* __restrict__ wkv_b,
    const void* __restrict__ wo, const void* __restrict__ nw,
    float* __restrict__ ws)
{
    const int isbf = ((const int*)ws)[OFF_FLAG];
    int i = blockIdx.x * 256 + threadIdx.x;
    int y = blockIdx.y;
    if (y == 0) {
        if (i < 768 * 768) { int k = i / 768, o = i - k * 768; ws[OFF_WOT + i] = ldin(wo, (size_t)o * 768 + k, isbf); }
    } else if (y == 1) {
        if (i < 768 * 128) { int k = i >> 7, o = i & 127; ws[OFF_WKVAT + i] = ldin(wkv_a, (size_t)o * 768 + k, isbf); }
    } else if (y == 2) {
        if (i < 768 * 64) { int k = i >> 6, o = i & 63; ws[OFF_WQAT + i] = ldin(wq_a, (size_t)o * 768 + k, isbf); }
    } else if (y == 3) {
        if (i < 64 * 768) { int k = i / 768, o = i - k * 768; ws[OFF_WQBT + i] = ldin(wq_b, (size_t)o * 64 + k, isbf); }
    } else if (y == 4) {
        if (i < 8 * 32 * 64) { int h = i >> 11; ws[OFF_QAF + i] = ldin(wkv_b, (size_t)h * 8192 + (i & 2047), isbf); }
    } else if (y == 5) { // out_absorbT [h][r][v] = wkv_b[h*128+32+v][r]
        if (i < 8 * 64 * 96) {
            int h = i / 6144, rem = i - h * 6144;
            int r = rem / 96, v = rem - r * 96;
            ws[OFF_OAT + i] = ldin(wkv_b, (size_t)h * 8192 + 2048 + v * 64 + r, isbf);
        }
    } else {
        if (i < 64)             ws[OFF_QLN + i]       = ldin(q_ln, i, isbf);
        else if (i < 128)       ws[OFF_KVLN + i - 64] = ldin(kv_ln, i - 64, isbf);
        else if (i < 128 + 768) ws[OFF_NW + i - 128]  = ldin(nw, i - 128, isbf);
    }
}

// ---------------------------------------------------------------------------
// k1: ckv = src @ wkv_a^T ; K'bf16[token][128] = [c_lat_n*w | rope(k_pe)],
//     VT bf16[b][64][2048] = c_lat_n*w transposed.  32 tokens/block.
// ---------------------------------------------------------------------------
__global__ __launch_bounds__(256) void k1_ckv(
    const void* __restrict__ src, const float* __restrict__ ws,
    ushort_t* __restrict__ Kbf, ushort_t* __restrict__ VTbf)
{
    const float* wkvaT = ws + OFF_WKVAT;
    const float* kvln  = ws + OFF_KVLN;
    const int isbf = ((const int*)ws)[OFF_FLAG];
    __shared__ float slds[32][68];
    __shared__ float ckv[32][132];
    int j = threadIdx.x;
    int t0 = blockIdx.x * 32;
    int o = j & 127, tg = j >> 7;
    float acc[16];
#pragma unroll
    for (int i = 0; i < 16; ++i) acc[i] = 0.f;

    for (int k0 = 0; k0 < 768; k0 += 64) {
        {
            int tt = j >> 3, kk = (j & 7) * 8;
            size_t off = (size_t)(t0 + tt) * 768 + k0 + kk;
            float* d = &slds[tt][kk];
            if (isbf) {
                uint4 u = *(const uint4*)((const ushort_t*)src + off);
                d[0] = bf2f(u.x & 0xffff); d[1] = bf2f(u.x >> 16);
                d[2] = bf2f(u.y & 0xffff); d[3] = bf2f(u.y >> 16);
                d[4] = bf2f(u.z & 0xffff); d[5] = bf2f(u.z >> 16);
                d[6] = bf2f(u.w & 0xffff); d[7] = bf2f(u.w >> 16);
            } else {
                const float4* p = (const float4*)((const float*)src + off);
                *(float4*)&d[0] = p[0];
                *(float4*)&d[4] = p[1];
            }
        }
        __syncthreads();
#pragma unroll 1
        for (int kk = 0; kk < 64; kk += 4) {
            float w0 = wkvaT[(k0 + kk) * 128 + o];
            float w1 = wkvaT[(k0 + kk + 1) * 128 + o];
            float w2 = wkvaT[(k0 + kk + 2) * 128 + o];
            float w3 = wkvaT[(k0 + kk + 3) * 128 + o];
#pragma unroll
            for (int i = 0; i < 16; ++i) {
                float4 s4 = *(const float4*)&slds[tg * 16 + i][kk];
                acc[i] += s4.x * w0 + s4.y * w1 + s4.z * w2 + s4.w * w3;
            }
        }
        __syncthreads();
    }
#pragma unroll
    for (int i = 0; i < 16; ++i) ckv[tg * 16 + i][o] = acc[i];
    __syncthreads();

    {
        int tt = j >> 3, l = j & 7;
        float ss = 0.f;
#pragma unroll
        for (int i = 0; i < 8; ++i) { float v = ckv[tt][l * 8 + i]; ss += v * v; }
        ss += __shfl_xor(ss, 1); ss += __shfl_xor(ss, 2); ss += __shfl_xor(ss, 4);
        float rs = rsqrtf(ss * (1.f / 64.f) + EPSF);
        size_t base = (size_t)(t0 + tt) * 128;
        ushort_t kb[8];
        float clw[8];
#pragma unroll
        for (int i = 0; i < 8; ++i) {
            int o2 = l * 8 + i;
            float cl = ckv[tt][o2] * rs;
            if (isbf) cl = bf2f(f2bf(cl));   // reference: .astype(bf16) before *w
            clw[i] = cl * kvln[o2];
            kb[i] = f2bf(clw[i]);
        }
        uint4 pack;
        pack.x = kb[0] | ((unsigned)kb[1] << 16); pack.y = kb[2] | ((unsigned)kb[3] << 16);
        pack.z = kb[4] | ((unsigned)kb[5] << 16); pack.w = kb[6] | ((unsigned)kb[7] << 16);
        *(uint4*)&Kbf[base + l * 8] = pack;
        int pos = (t0 + tt) & 2047;
        ushort_t r0[4], r1[4];
#pragma unroll
        for (int i = 0; i < 4; ++i) {
            int p = l * 4 + i;
            float inv = exp2f(-(float)p * L2_10000_OVER_32);
            float ang = (float)pos * inv;
            float sn = sinf(ang), cs = cosf(ang);
            float e = ckv[tt][64 + 2 * p], od = ckv[tt][64 + 2 * p + 1];
            r0[i] = f2bf(e * cs - od * sn);
            r1[i] = f2bf(od * cs + e * sn);
        }
        uint2 p0, p1;
        p0.x = r0[0] | ((unsigned)r0[1] << 16); p0.y = r0[2] | ((unsigned)r0[3] << 16);
        p1.x = r1[0] | ((unsigned)r1[1] << 16); p1.y = r1[2] | ((unsigned)r1[3] << 16);
        *(uint2*)&Kbf[base + 64 + l * 4] = p0;
        *(uint2*)&Kbf[base + 96 + l * 4] = p1;
        // write normalized c_lat back to LDS for the VT transpose phase
#pragma unroll
        for (int i = 0; i < 8; ++i) ckv[tt][l * 8 + i] = clw[i];
    }
    __syncthreads();
    {   // VT[b][r][t] = c_lat_n[t][r]
        int t = j & 31, rb = (j >> 5) * 8;
        int bb = t0 >> 11, col = (t0 & 2047) + t;
#pragma unroll
        for (int i = 0; i < 8; ++i) {
            int r = rb + i;
            VTbf[((size_t)(bb * 64 + r)) * 2048 + col] = f2bf(ckv[t][r]);
        }
    }
}

// ---------------------------------------------------------------------------
// k2: q = rmsnorm(src@wq_a^T)@wq_b^T ; per head: q_lat = q_nope@q_absorb,
//     q_pe = rope(q_pe). Store Q' bf16 [b][h][2048][128] * SCALE.
// ---------------------------------------------------------------------------
__global__ __launch_bounds__(256) void k2_q(
    const void* __restrict__ src, const float* __restrict__ ws, ushort_t* __restrict__ Qbf)
{
    const float* wqaT = ws + OFF_WQAT;
    const float* wqbT = ws + OFF_WQBT;
    const float* qaF  = ws + OFF_QAF;
    const float* qln  = ws + OFF_QLN;
    const int isbf = ((const int*)ws)[OFF_FLAG];
    __shared__ float slds[8][68];
    __shared__ float tlds[8][68];
    __shared__ float qlds[8][768];
    int j = threadIdx.x;
    int t0 = blockIdx.x * 8;

    {
        int o = j & 63, tg = j >> 6;
        float a0 = 0.f, a1 = 0.f;
        for (int k0 = 0; k0 < 768; k0 += 64) {
            {
                int tt = j >> 5, kk = (j & 31) * 2;
                size_t off = (size_t)(t0 + tt) * 768 + k0 + kk;
                if (isbf) {
                    unsigned int u = *(const unsigned int*)((const ushort_t*)src + off);
                    slds[tt][kk] = bf2f(u & 0xffff); slds[tt][kk + 1] = bf2f(u >> 16);
                } else {
                    const float* p = (const float*)src + off;
                    slds[tt][kk] = p[0]; slds[tt][kk + 1] = p[1];
                }
            }
            __syncthreads();
#pragma unroll 1
            for (int kk = 0; kk < 64; kk += 4) {
                float w0 = wqaT[(k0 + kk) * 64 + o], w1 = wqaT[(k0 + kk + 1) * 64 + o];
                float w2 = wqaT[(k0 + kk + 2) * 64 + o], w3 = wqaT[(k0 + kk + 3) * 64 + o];
                float4 s0 = *(const float4*)&slds[tg * 2][kk];
                float4 s1 = *(const float4*)&slds[tg * 2 + 1][kk];
                a0 += s0.x * w0 + s0.y * w1 + s0.z * w2 + s0.w * w3;
                a1 += s1.x * w0 + s1.y * w1 + s1.z * w2 + s1.w * w3;
            }
            __syncthreads();
        }
        tlds[tg * 2][o] = a0; tlds[tg * 2 + 1][o] = a1;
    }
    __syncthreads();
    {
        int tt = j >> 5, l = j & 31;
        float v0 = tlds[tt][l * 2], v1 = tlds[tt][l * 2 + 1];
        float ss = v0 * v0 + v1 * v1;
        ss += __shfl_xor(ss, 1); ss += __shfl_xor(ss, 2); ss += __shfl_xor(ss, 4);
        ss += __shfl_xor(ss, 8); ss += __shfl_xor(ss, 16);
        float rs = rsqrtf(ss * (1.f / 64.f) + EPSF);
        float n0 = v0 * rs, n1 = v1 * rs;
        if (isbf) { n0 = bf2f(f2bf(n0)); n1 = bf2f(f2bf(n1)); }
        tlds[tt][l * 2]     = n0 * qln[l * 2];
        tlds[tt][l * 2 + 1] = n1 * qln[l * 2 + 1];
    }
    __syncthreads();
    {
        float qa[8][3];
#pragma unroll
        for (int i = 0; i < 8; ++i) { qa[i][0] = 0.f; qa[i][1] = 0.f; qa[i][2] = 0.f; }
#pragma unroll 1
        for (int k = 0; k < 64; k += 4) {
            float w[4][3];
#pragma unroll
            for (int kk = 0; kk < 4; ++kk) {
                const float* wp = wqbT + (size_t)(k + kk) * 768 + j;
                w[kk][0] = wp[0]; w[kk][1] = wp[256]; w[kk][2] = wp[512];
            }
#pragma unroll
            for (int i = 0; i < 8; ++i) {
                float4 t4 = *(const float4*)&tlds[i][k];
                qa[i][0] += t4.x * w[0][0] + t4.y * w[1][0] + t4.z * w[2][0] + t4.w * w[3][0];
                qa[i][1] += t4.x * w[0][1] + t4.y * w[1][1] + t4.z * w[2][1] + t4.w * w[3][1];
                qa[i][2] += t4.x * w[0][2] + t4.y * w[1][2] + t4.z * w[2][2] + t4.w * w[3][2];
            }
        }
#pragma unroll
        for (int i = 0; i < 8; ++i) {
            qlds[i][j] = qa[i][0]; qlds[i][j + 256] = qa[i][1]; qlds[i][j + 512] = qa[i][2];
        }
    }
    __syncthreads();
    {
        int wv = j >> 6, lane = j & 63;
        for (int u = wv * 16; u < wv * 16 + 16; ++u) {
            int tt = u >> 3, h = u & 7;
            int qb = h * 96;
            float acc = 0.f;
#pragma unroll 4
            for (int d = 0; d < 32; ++d) acc += qlds[tt][qb + d] * qaF[(h * 32 + d) * 64 + lane];
            int token = t0 + tt, pos = token & 2047;
            size_t qoff = ((size_t)((token >> 11) * 8 + h) * 2048 + pos) * 128;
            Qbf[qoff + lane] = f2bf(acc * SCALE);
            if (lane < 32) {
                int p = lane;
                float e = qlds[tt][qb + 32 + 2 * p], od = qlds[tt][qb + 32 + 2 * p + 1];
                float inv = exp2f(-(float)p * L2_10000_OVER_32);
                float ang = (float)pos * inv;
                float sn = sinf(ang), cs = cosf(ang);
                Qbf[qoff + 64 + p] = f2bf((e * cs - od * sn) * SCALE);
                Qbf[qoff + 96 + p] = f2bf((od * cs + e * sn) * SCALE);
            }
        }
    }
}

// ---------------------------------------------------------------------------
// k3: MFMA flash attention. grid (32,8,4): 64 q/block (16 q/wave), K-tiles 64.
// LDS: Kt[64][136] bf16 | Vt[64][72] bf16 | P per-wave [16][72] bf16. 35840 B.
// Epilogue: MFMA absorb (O @ out_absorb) -> ctx_flat fp32.
// ---------------------------------------------------------------------------
__global__ __launch_bounds__(256, 4) void k3_attn(
    const ushort_t* __restrict__ Qbf, const ushort_t* __restrict__ Kbf,
    const ushort_t* __restrict__ VTbf, const float* __restrict__ oaT,
    float* __restrict__ ctxf)
{
    __shared__ __align__(16) ushort_t LDS[17920];
    ushort_t* Kt = LDS;                    // [64][136]
    ushort_t* Vt = LDS + 8704;             // [64][72]
    ushort_t* Pw = LDS + 8704 + 4608;      // [4][16][72]
    int j = threadIdx.x;
    int b = blockIdx.z, h = blockIdx.y, q0g = blockIdx.x * 64;
    int w = j >> 6, lane = j & 63;
    int tl = lane & 15, qd = lane >> 4;
    ushort_t* Pme = Pw + w * (16 * 72);

    // Q fragments: lane holds Q[q = q0g + w*16 + tl][k = ks*32 + qd*8 + 0..7]
    bf8_t qfrag[4];
    {
        const ushort_t* qp = Qbf + ((size_t)((b * 8 + h) * 2048) + q0g + w * 16 + tl) * 128 + qd * 8;
#pragma unroll
        for (int ks = 0; ks < 4; ++ks) qfrag[ks] = *(const bf8_t*)(qp + ks * 32);
    }
    f4_t Oacc[4];
#pragma unroll
    for (int nt = 0; nt < 4; ++nt) Oacc[nt] = (f4_t){0.f, 0.f, 0.f, 0.f};
    float mrow[4] = {-1e30f, -1e30f, -1e30f, -1e30f};
    float lrow[4] = {0.f, 0.f, 0.f, 0.f};

    const size_t kbase = (size_t)b * 2048 * 128;
    const size_t vbase = (size_t)b * 64 * 2048;

    for (int it = 0; it < 32; ++it) {
        __syncthreads();
        {   // stage Kt (64 x 128 bf16)
            int r = j >> 2, c0 = (j & 3) * 32;
            const uint4* gp = (const uint4*)(Kbf + kbase + (size_t)(it * 64 + r) * 128 + c0);
            uint4 a0 = gp[0], a1 = gp[1], a2 = gp[2], a3 = gp[3];
            uint4* dp = (uint4*)(Kt + r * 136 + c0);
            dp[0] = a0; dp[1] = a1; dp[2] = a2; dp[3] = a3;
        }
        {   // stage Vt (64 d x 64 t bf16)
            int d = j >> 2, c0 = (j & 3) * 16;
            const uint4* gp = (const uint4*)(VTbf + vbase + (size_t)d * 2048 + it * 64 + c0);
            uint4 a0 = gp[0], a1 = gp[1];
            uint4* dp = (uint4*)(Vt + d * 72 + c0);
            dp[0] = a0; dp[1] = a1;
        }
        __syncthreads();
        // scores: S[q=qd*4+r][t=nt*16+tl] in C-layout
        f4_t S[4];
#pragma unroll
        for (int nt = 0; nt < 4; ++nt) {
            f4_t c = (f4_t){0.f, 0.f, 0.f, 0.f};
#pragma unroll
            for (int ks = 0; ks < 4; ++ks) {
                bf8_t kf = *(const bf8_t*)(Kt + (nt * 16 + tl) * 136 + ks * 32 + qd * 8);
                c = __builtin_amdgcn_mfma_f32_16x16x32_bf16(qfrag[ks], kf, c, 0, 0, 0);
            }
            S[nt] = c;
        }
        // online softmax (rows q = qd*4 + r; reduce over 16 lanes of same quad)
        float mt[4], al[4], rsum[4];
#pragma unroll
        for (int r = 0; r < 4; ++r)
            mt[r] = fmaxf(fmaxf(S[0][r], S[1][r]), fmaxf(S[2][r], S[3][r]));
#pragma unroll
        for (int mask = 1; mask < 16; mask <<= 1)
#pragma unroll
            for (int r = 0; r < 4; ++r) mt[r] = fmaxf(mt[r], __shfl_xor(mt[r], mask));
#pragma unroll
        for (int r = 0; r < 4; ++r) {
            float mn = fmaxf(mrow[r], mt[r]);
            al[r] = __expf(mrow[r] - mn);
            mrow[r] = mn; rsum[r] = 0.f;
        }
#pragma unroll
        for (int nt = 0; nt < 4; ++nt)
#pragma unroll
            for (int r = 0; r < 4; ++r) {
                float p = __expf(S[nt][r] - mrow[r]);
                S[nt][r] = p; rsum[r] += p;
            }
#pragma unroll
        for (int mask = 1; mask < 16; mask <<= 1)
#pragma unroll
            for (int r = 0; r < 4; ++r) rsum[r] += __shfl_xor(rsum[r], mask);
#pragma unroll
        for (int r = 0; r < 4; ++r) lrow[r] = lrow[r] * al[r] + rsum[r];
        // P -> LDS (bf16, [q][t] A-layout source)
#pragma unroll
        for (int nt = 0; nt < 4; ++nt)
#pragma unroll
            for (int r = 0; r < 4; ++r)
                Pme[(qd * 4 + r) * 72 + nt * 16 + tl] = f2bf(S[nt][r]);
#pragma unroll
        for (int nt = 0; nt < 4; ++nt)
#pragma unroll
            for (int r = 0; r < 4; ++r) Oacc[nt][r] *= al[r];
        __syncthreads();
        // PV: O[q][d] += P[q][t] * V[t][d]; B-frag from Vt[d][t]
        bf8_t pf[2];
#pragma unroll
        for (int ks = 0; ks < 2; ++ks) pf[ks] = *(const bf8_t*)(Pme + tl * 72 + ks * 32 + qd * 8);
#pragma unroll
        for (int nt = 0; nt < 4; ++nt)
#pragma unroll
            for (int ks = 0; ks < 2; ++ks) {
                bf8_t vf = *(const bf8_t*)(Vt + (nt * 16 + tl) * 72 + ks * 32 + qd * 8);
                Oacc[nt] = __builtin_amdgcn_mfma_f32_16x16x32_bf16(pf[ks], vf, Oacc[nt], 0, 0, 0);
            }
    }
    __syncthreads();
    // normalized O -> Pme (bf16), stage oa^T bf16 [v=96][r=72pitch] into Kt area
    {
        float invl[4];
#pragma unroll
        for (int r = 0; r < 4; ++r) invl[r] = 1.f / lrow[r];
#pragma unroll
        for (int nt = 0; nt < 4; ++nt)
#pragma unroll
            for (int r = 0; r < 4; ++r)
                Pme[(qd * 4 + r) * 72 + nt * 16 + tl] = f2bf(Oacc[nt][r] * invl[r]);
    }
    ushort_t* OA = LDS;  // [96][72]
    for (int e = j; e < 96 * 64; e += 256) {
        int v = e >> 6, r = e & 63;
        OA[v * 72 + r] = f2bf(oaT[h * 6144 + r * 96 + v]);
    }
    __syncthreads();
    {   // ctx[q][v] = sum_r O[q][r] * oa[r][v]
        bf8_t of[2];
#pragma unroll
        for (int ks = 0; ks < 2; ++ks) of[ks] = *(const bf8_t*)(Pme + tl * 72 + ks * 32 + qd * 8);
#pragma unroll
        for (int nt = 0; nt < 6; ++nt) {
            f4_t c = (f4_t){0.f, 0.f, 0.f, 0.f};
#pragma unroll
            for (int ks = 0; ks < 2; ++ks) {
                bf8_t af = *(const bf8_t*)(OA + (nt * 16 + tl) * 72 + ks * 32 + qd * 8);
                c = __builtin_amdgcn_mfma_f32_16x16x32_bf16(of[ks], af, c, 0, 0, 0);
            }
#pragma unroll
            for (int r = 0; r < 4; ++r) {
                size_t tok = (size_t)(b * 2048 + q0g + w * 16 + qd * 4 + r);
                ctxf[tok * 768 + h * 96 + nt * 16 + tl] = c[r];
            }
        }
    }
}

// ---------------------------------------------------------------------------
// k5: attn_out = ctx_flat @ wo^T ; y = src + attn_out ; out = rmsnorm(y)*w
// ---------------------------------------------------------------------------
__global__ __launch_bounds__(256) void k5_out(
    const void* __restrict__ src, const float* __restrict__ ws,
    const float* __restrict__ ctxf, void* __restrict__ out)
{
    const float* woT = ws + OFF_WOT;
    const float* nw  = ws + OFF_NW;
    const int isbf = ((const int*)ws)[OFF_FLAG];
    __shared__ float clds[16][132];
    __shared__ float ylds[16][772];
    int j = threadIdx.x;
    int t0 = blockIdx.x * 16;
    float acc[16][3];
#pragma unroll
    for (int tt = 0; tt < 16; ++tt) { acc[tt][0] = 0.f; acc[tt][1] = 0.f; acc[tt][2] = 0.f; }

    for (int k0 = 0; k0 < 768; k0 += 128) {
        {
            int tt = j >> 4, kk = (j & 15) * 8;
            const float* p = ctxf + (size_t)(t0 + tt) * 768 + k0 + kk;
            *(float4*)&clds[tt][kk]     = ((const float4*)p)[0];
            *(float4*)&clds[tt][kk + 4] = ((const float4*)p)[1];
        }
        __syncthreads();
#pragma unroll 1
        for (int k = 0; k < 128; k += 4) {
            float w[4][3];
#pragma unroll
            for (int kk = 0; kk < 4; ++kk) {
                const float* wp = woT + (size_t)(k0 + k + kk) * 768 + j;
                w[kk][0] = wp[0]; w[kk][1] = wp[256]; w[kk][2] = wp[512];
            }
#pragma unroll
            for (int tt = 0; tt < 16; ++tt) {
                float4 c4 = *(const float4*)&clds[tt][k];
                acc[tt][0] += c4.x * w[0][0] + c4.y * w[1][0] + c4.z * w[2][0] + c4.w * w[3][0];
                acc[tt][1] += c4.x * w[0][1] + c4.y * w[1][1] + c4.z * w[2][1] + c4.w * w[3][1];
                acc[tt][2] += c4.x * w[0][2] + c4.y * w[1][2] + c4.z * w[2][2] + c4.w * w[3][2];
            }
        }
        __syncthreads();
    }
#pragma unroll
    for (int tt = 0; tt < 16; ++tt) {
        size_t base = (size_t)(t0 + tt) * 768;
        ylds[tt][j]       = acc[tt][0] + ldin(src, base + j, isbf);
        ylds[tt][j + 256] = acc[tt][1] + ldin(src, base + j + 256, isbf);
        ylds[tt][j + 512] = acc[tt][2] + ldin(src, base + j + 512, isbf);
    }
    __syncthreads();
    {
        int tt = j >> 4, l = j & 15;
        float ss = 0.f;
#pragma unroll 1
        for (int i = 0; i < 48; ++i) { float v = ylds[tt][l + 16 * i]; ss += v * v; }
        ss += __shfl_xor(ss, 1); ss += __shfl_xor(ss, 2); ss += __shfl_xor(ss, 4); ss += __shfl_xor(ss, 8);
        float rs = rsqrtf(ss * (1.f / 768.f) + EPSF);
        size_t base = (size_t)(t0 + tt) * 768;
#pragma unroll 1
        for (int i = 0; i < 48; ++i) {
            int o = l + 16 * i;
            float yv = ylds[tt][o] * rs;
            if (isbf) {
                yv = bf2f(f2bf(yv));
                ((ushort_t*)out)[base + o] = f2bf(yv * nw[o]);
            } else {
                ((float*)out)[base + o] = yv * nw[o];
            }
        }
    }
}

// ---------------------------------------------------------------------------
extern "C" void kernel_launch(void* const* d_in, const int* in_sizes, int n_in,
                              void* d_out, int out_size, void* d_ws, size_t ws_size,
                              hipStream_t stream)
{
    const void* src   = d_in[0];
    const void* wq_a  = d_in[1];
    const void* q_ln  = d_in[2];
    const void* wq_b  = d_in[3];
    const void* wkv_a = d_in[4];
    const void* kv_ln = d_in[5];
    const void* wkv_b = d_in[6];
    const void* wo    = d_in[7];
    const void* nw    = d_in[8];
    float* ws = (float*)d_ws;
    ushort_t* Kbf  = (ushort_t*)(ws + OFF_KBF);
    ushort_t* VTbf = (ushort_t*)(ws + OFF_VTB);
    ushort_t* Qbf  = (ushort_t*)(ws + OFF_QBF);

    det_k<<<dim3(1), dim3(1), 0, stream>>>((const unsigned int*)nw, (int*)ws + OFF_FLAG);
    prep_k<<<dim3(2304, 7), dim3(256), 0, stream>>>(wq_a, q_ln, wq_b, wkv_a, kv_ln, wkv_b, wo, nw, ws);
    k1_ckv<<<dim3(TOK / 32), dim3(256), 0, stream>>>(src, ws, Kbf, VTbf);
    k2_q<<<dim3(TOK / 8), dim3(256), 0, stream>>>(src, ws, Qbf);
    k3_attn<<<dim3(32, 8, 4), dim3(256), 0, stream>>>(Qbf, Kbf, VTbf, ws + OFF_OAT, ws + OFF_CTXF);
    k5_out<<<dim3(TOK / 16), dim3(256), 0, stream>>>(src, ws, ws + OFF_CTXF, d_out);
}

// Round 4
// 508.311 us; speedup vs baseline: 3.3055x; 1.2103x over previous
//
#include <hip/hip_runtime.h>

// ---------------------------------------------------------------------------
// MLA prefill (B=4, S=2048, D=768, H=8, q_rank=kv_rank=rope=64, nope=32, v=96)
// Round 4: MFMA flash attention (k3) + MFMA wo-GEMM w/ fused residual+RMSNorm
// epilogue (k5). ctx and wo now bf16. Projections (k1/k2) still fp32 vector.
// ---------------------------------------------------------------------------

#define DEV static __device__ __forceinline__
typedef unsigned short ushort_t;
typedef __attribute__((ext_vector_type(8))) short bf8_t;
typedef __attribute__((ext_vector_type(4))) float f4_t;

DEV float bf2f(unsigned int u) {
    union { float f; unsigned int i; } x; x.i = u << 16; return x.f;
}
DEV ushort_t f2bf(float f) {
    union { float f; unsigned int u; } x; x.f = f;
    unsigned int u = x.u;
    return (ushort_t)((u + 0x7fffu + ((u >> 16) & 1u)) >> 16);
}
DEV float ldin(const void* p, size_t i, int isbf) {
    return isbf ? bf2f(((const ushort_t*)p)[i]) : ((const float*)p)[i];
}

constexpr int   TOK   = 4 * 2048;                         // 8192 tokens
constexpr float EPSF  = 1e-6f;
constexpr float SCALE = 0.10206207261596575f;             // 96^-0.5
constexpr float L2_10000_OVER_32 = 0.4152410118609203f;   // log2(10000)/32

// workspace layout (float offsets)
constexpr size_t OFF_WOT   = 0;                 // wo bf16 [768][768] (row-major copy)
constexpr size_t OFF_WKVAT = 589824;            // wkv_aT [768][128] fp32
constexpr size_t OFF_WQAT  = 688128;            // wq_aT  [768][64] fp32
constexpr size_t OFF_WQBT  = 737280;            // wq_bT  [64][768] fp32
constexpr size_t OFF_QAF   = 786432;            // q_absorb [8][32][64] fp32
constexpr size_t OFF_OAT   = 802816;            // out_absorbT [8][r=64][v=96] fp32
constexpr size_t OFF_QLN   = 851968;
constexpr size_t OFF_KVLN  = 852032;
constexpr size_t OFF_NW    = 852096;
constexpr size_t OFF_FLAG  = 852864;
constexpr size_t OFF_CTXF  = 852880;            // ctx bf16 [8192][768] (in ushort units)
constexpr size_t OFF_KBF   = 7144336;           // K' bf16 [4][2048][128]
constexpr size_t OFF_VTB   = 7668624;           // V^T bf16 [4][64][2048]
constexpr size_t OFF_QBF   = 7930768;           // Q' bf16 [4][8][2048][128]

// ---------------------------------------------------------------------------
__global__ void det_k(const unsigned int* __restrict__ nw_u, int* __restrict__ flag) {
    *flag = ((nw_u[0] & 0xffffu) != 0u) ? 1 : 0;
}

// ---------------------------------------------------------------------------
__global__ __launch_bounds__(256) void prep_k(
    const void* __restrict__ wq_a, const void* __restrict__ q_ln,
    const void* __restrict__ wq_b, const void* __restrict__ wkv_a,
    const void* __restrict__ kv_ln, const void* __restrict__ wkv_b,
    const void* __restrict__ wo, const void* __restrict__ nw,
    float* __restrict__ ws)
{
    const int isbf = ((const int*)ws)[OFF_FLAG];
    int i = blockIdx.x * 256 + threadIdx.x;
    int y = blockIdx.y;
    if (y == 0) {        // wo -> bf16 straight copy (row-major [o][k])
        if (i < 768 * 768) {
            ushort_t* wob = (ushort_t*)(ws + OFF_WOT);
            wob[i] = isbf ? ((const ushort_t*)wo)[i] : f2bf(((const float*)wo)[i]);
        }
    } else if (y == 1) {
        if (i < 768 * 128) { int k = i >> 7, o = i & 127; ws[OFF_WKVAT + i] = ldin(wkv_a, (size_t)o * 768 + k, isbf); }
    } else if (y == 2) {
        if (i < 768 * 64) { int k = i >> 6, o = i & 63; ws[OFF_WQAT + i] = ldin(wq_a, (size_t)o * 768 + k, isbf); }
    } else if (y == 3) {
        if (i < 64 * 768) { int k = i / 768, o = i - k * 768; ws[OFF_WQBT + i] = ldin(wq_b, (size_t)o * 64 + k, isbf); }
    } else if (y == 4) {
        if (i < 8 * 32 * 64) { int h = i >> 11; ws[OFF_QAF + i] = ldin(wkv_b, (size_t)h * 8192 + (i & 2047), isbf); }
    } else if (y == 5) { // out_absorbT [h][r][v] = wkv_b[h*128+32+v][r]
        if (i < 8 * 64 * 96) {
            int h = i / 6144, rem = i - h * 6144;
            int r = rem / 96, v = rem - r * 96;
            ws[OFF_OAT + i] = ldin(wkv_b, (size_t)h * 8192 + 2048 + v * 64 + r, isbf);
        }
    } else {
        if (i < 64)             ws[OFF_QLN + i]       = ldin(q_ln, i, isbf);
        else if (i < 128)       ws[OFF_KVLN + i - 64] = ldin(kv_ln, i - 64, isbf);
        else if (i < 128 + 768) ws[OFF_NW + i - 128]  = ldin(nw, i - 128, isbf);
    }
}

// ---------------------------------------------------------------------------
// k1: ckv = src @ wkv_a^T ; K'bf16[token][128] = [c_lat_n*w | rope(k_pe)],
//     VT bf16[b][64][2048] = c_lat_n*w transposed.  32 tokens/block.
// ---------------------------------------------------------------------------
__global__ __launch_bounds__(256) void k1_ckv(
    const void* __restrict__ src, const float* __restrict__ ws,
    ushort_t* __restrict__ Kbf, ushort_t* __restrict__ VTbf)
{
    const float* wkvaT = ws + OFF_WKVAT;
    const float* kvln  = ws + OFF_KVLN;
    const int isbf = ((const int*)ws)[OFF_FLAG];
    __shared__ float slds[32][68];
    __shared__ float ckv[32][132];
    int j = threadIdx.x;
    int t0 = blockIdx.x * 32;
    int o = j & 127, tg = j >> 7;
    float acc[16];
#pragma unroll
    for (int i = 0; i < 16; ++i) acc[i] = 0.f;

    for (int k0 = 0; k0 < 768; k0 += 64) {
        {
            int tt = j >> 3, kk = (j & 7) * 8;
            size_t off = (size_t)(t0 + tt) * 768 + k0 + kk;
            float* d = &slds[tt][kk];
            if (isbf) {
                uint4 u = *(const uint4*)((const ushort_t*)src + off);
                d[0] = bf2f(u.x & 0xffff); d[1] = bf2f(u.x >> 16);
                d[2] = bf2f(u.y & 0xffff); d[3] = bf2f(u.y >> 16);
                d[4] = bf2f(u.z & 0xffff); d[5] = bf2f(u.z >> 16);
                d[6] = bf2f(u.w & 0xffff); d[7] = bf2f(u.w >> 16);
            } else {
                const float4* p = (const float4*)((const float*)src + off);
                *(float4*)&d[0] = p[0];
                *(float4*)&d[4] = p[1];
            }
        }
        __syncthreads();
#pragma unroll 1
        for (int kk = 0; kk < 64; kk += 4) {
            float w0 = wkvaT[(k0 + kk) * 128 + o];
            float w1 = wkvaT[(k0 + kk + 1) * 128 + o];
            float w2 = wkvaT[(k0 + kk + 2) * 128 + o];
            float w3 = wkvaT[(k0 + kk + 3) * 128 + o];
#pragma unroll
            for (int i = 0; i < 16; ++i) {
                float4 s4 = *(const float4*)&slds[tg * 16 + i][kk];
                acc[i] += s4.x * w0 + s4.y * w1 + s4.z * w2 + s4.w * w3;
            }
        }
        __syncthreads();
    }
#pragma unroll
    for (int i = 0; i < 16; ++i) ckv[tg * 16 + i][o] = acc[i];
    __syncthreads();

    {
        int tt = j >> 3, l = j & 7;
        float ss = 0.f;
#pragma unroll
        for (int i = 0; i < 8; ++i) { float v = ckv[tt][l * 8 + i]; ss += v * v; }
        ss += __shfl_xor(ss, 1); ss += __shfl_xor(ss, 2); ss += __shfl_xor(ss, 4);
        float rs = rsqrtf(ss * (1.f / 64.f) + EPSF);
        size_t base = (size_t)(t0 + tt) * 128;
        ushort_t kb[8];
        float clw[8];
#pragma unroll
        for (int i = 0; i < 8; ++i) {
            int o2 = l * 8 + i;
            float cl = ckv[tt][o2] * rs;
            if (isbf) cl = bf2f(f2bf(cl));   // reference: .astype(bf16) before *w
            clw[i] = cl * kvln[o2];
            kb[i] = f2bf(clw[i]);
        }
        uint4 pack;
        pack.x = kb[0] | ((unsigned)kb[1] << 16); pack.y = kb[2] | ((unsigned)kb[3] << 16);
        pack.z = kb[4] | ((unsigned)kb[5] << 16); pack.w = kb[6] | ((unsigned)kb[7] << 16);
        *(uint4*)&Kbf[base + l * 8] = pack;
        int pos = (t0 + tt) & 2047;
        ushort_t r0[4], r1[4];
#pragma unroll
        for (int i = 0; i < 4; ++i) {
            int p = l * 4 + i;
            float inv = exp2f(-(float)p * L2_10000_OVER_32);
            float ang = (float)pos * inv;
            float sn = sinf(ang), cs = cosf(ang);
            float e = ckv[tt][64 + 2 * p], od = ckv[tt][64 + 2 * p + 1];
            r0[i] = f2bf(e * cs - od * sn);
            r1[i] = f2bf(od * cs + e * sn);
        }
        uint2 p0, p1;
        p0.x = r0[0] | ((unsigned)r0[1] << 16); p0.y = r0[2] | ((unsigned)r0[3] << 16);
        p1.x = r1[0] | ((unsigned)r1[1] << 16); p1.y = r1[2] | ((unsigned)r1[3] << 16);
        *(uint2*)&Kbf[base + 64 + l * 4] = p0;
        *(uint2*)&Kbf[base + 96 + l * 4] = p1;
#pragma unroll
        for (int i = 0; i < 8; ++i) ckv[tt][l * 8 + i] = clw[i];
    }
    __syncthreads();
    {   // VT[b][r][t] = c_lat_n[t][r]
        int t = j & 31, rb = (j >> 5) * 8;
        int bb = t0 >> 11, col = (t0 & 2047) + t;
#pragma unroll
        for (int i = 0; i < 8; ++i) {
            int r = rb + i;
            VTbf[((size_t)(bb * 64 + r)) * 2048 + col] = f2bf(ckv[t][r]);
        }
    }
}

// ---------------------------------------------------------------------------
// k2: q = rmsnorm(src@wq_a^T)@wq_b^T ; per head: q_lat = q_nope@q_absorb,
//     q_pe = rope(q_pe). Store Q' bf16 [b][h][2048][128] * SCALE.
// ---------------------------------------------------------------------------
__global__ __launch_bounds__(256) void k2_q(
    const void* __restrict__ src, const float* __restrict__ ws, ushort_t* __restrict__ Qbf)
{
    const float* wqaT = ws + OFF_WQAT;
    const float* wqbT = ws + OFF_WQBT;
    const float* qaF  = ws + OFF_QAF;
    const float* qln  = ws + OFF_QLN;
    const int isbf = ((const int*)ws)[OFF_FLAG];
    __shared__ float slds[8][68];
    __shared__ float tlds[8][68];
    __shared__ float qlds[8][768];
    int j = threadIdx.x;
    int t0 = blockIdx.x * 8;

    {
        int o = j & 63, tg = j >> 6;
        float a0 = 0.f, a1 = 0.f;
        for (int k0 = 0; k0 < 768; k0 += 64) {
            {
                int tt = j >> 5, kk = (j & 31) * 2;
                size_t off = (size_t)(t0 + tt) * 768 + k0 + kk;
                if (isbf) {
                    unsigned int u = *(const unsigned int*)((const ushort_t*)src + off);
                    slds[tt][kk] = bf2f(u & 0xffff); slds[tt][kk + 1] = bf2f(u >> 16);
                } else {
                    const float* p = (const float*)src + off;
                    slds[tt][kk] = p[0]; slds[tt][kk + 1] = p[1];
                }
            }
            __syncthreads();
#pragma unroll 1
            for (int kk = 0; kk < 64; kk += 4) {
                float w0 = wqaT[(k0 + kk) * 64 + o], w1 = wqaT[(k0 + kk + 1) * 64 + o];
                float w2 = wqaT[(k0 + kk + 2) * 64 + o], w3 = wqaT[(k0 + kk + 3) * 64 + o];
                float4 s0 = *(const float4*)&slds[tg * 2][kk];
                float4 s1 = *(const float4*)&slds[tg * 2 + 1][kk];
                a0 += s0.x * w0 + s0.y * w1 + s0.z * w2 + s0.w * w3;
                a1 += s1.x * w0 + s1.y * w1 + s1.z * w2 + s1.w * w3;
            }
            __syncthreads();
        }
        tlds[tg * 2][o] = a0; tlds[tg * 2 + 1][o] = a1;
    }
    __syncthreads();
    {
        int tt = j >> 5, l = j & 31;
        float v0 = tlds[tt][l * 2], v1 = tlds[tt][l * 2 + 1];
        float ss = v0 * v0 + v1 * v1;
        ss += __shfl_xor(ss, 1); ss += __shfl_xor(ss, 2); ss += __shfl_xor(ss, 4);
        ss += __shfl_xor(ss, 8); ss += __shfl_xor(ss, 16);
        float rs = rsqrtf(ss * (1.f / 64.f) + EPSF);
        float n0 = v0 * rs, n1 = v1 * rs;
        if (isbf) { n0 = bf2f(f2bf(n0)); n1 = bf2f(f2bf(n1)); }
        tlds[tt][l * 2]     = n0 * qln[l * 2];
        tlds[tt][l * 2 + 1] = n1 * qln[l * 2 + 1];
    }
    __syncthreads();
    {
        float qa[8][3];
#pragma unroll
        for (int i = 0; i < 8; ++i) { qa[i][0] = 0.f; qa[i][1] = 0.f; qa[i][2] = 0.f; }
#pragma unroll 1
        for (int k = 0; k < 64; k += 4) {
            float w[4][3];
#pragma unroll
            for (int kk = 0; kk < 4; ++kk) {
                const float* wp = wqbT + (size_t)(k + kk) * 768 + j;
                w[kk][0] = wp[0]; w[kk][1] = wp[256]; w[kk][2] = wp[512];
            }
#pragma unroll
            for (int i = 0; i < 8; ++i) {
                float4 t4 = *(const float4*)&tlds[i][k];
                qa[i][0] += t4.x * w[0][0] + t4.y * w[1][0] + t4.z * w[2][0] + t4.w * w[3][0];
                qa[i][1] += t4.x * w[0][1] + t4.y * w[1][1] + t4.z * w[2][1] + t4.w * w[3][1];
                qa[i][2] += t4.x * w[0][2] + t4.y * w[1][2] + t4.z * w[2][2] + t4.w * w[3][2];
            }
        }
#pragma unroll
        for (int i = 0; i < 8; ++i) {
            qlds[i][j] = qa[i][0]; qlds[i][j + 256] = qa[i][1]; qlds[i][j + 512] = qa[i][2];
        }
    }
    __syncthreads();
    {
        int wv = j >> 6, lane = j & 63;
        for (int u = wv * 16; u < wv * 16 + 16; ++u) {
            int tt = u >> 3, h = u & 7;
            int qb = h * 96;
            float acc = 0.f;
#pragma unroll 4
            for (int d = 0; d < 32; ++d) acc += qlds[tt][qb + d] * qaF[(h * 32 + d) * 64 + lane];
            int token = t0 + tt, pos = token & 2047;
            size_t qoff = ((size_t)((token >> 11) * 8 + h) * 2048 + pos) * 128;
            Qbf[qoff + lane] = f2bf(acc * SCALE);
            if (lane < 32) {
                int p = lane;
                float e = qlds[tt][qb + 32 + 2 * p], od = qlds[tt][qb + 32 + 2 * p + 1];
                float inv = exp2f(-(float)p * L2_10000_OVER_32);
                float ang = (float)pos * inv;
                float sn = sinf(ang), cs = cosf(ang);
                Qbf[qoff + 64 + p] = f2bf((e * cs - od * sn) * SCALE);
                Qbf[qoff + 96 + p] = f2bf((od * cs + e * sn) * SCALE);
            }
        }
    }
}

// ---------------------------------------------------------------------------
// k3: MFMA flash attention. grid (32,8,4): 64 q/block (16 q/wave), K-tiles 64.
// LDS: Kt[64][136] bf16 | Vt[64][72] bf16 | P per-wave [16][72] bf16.
// Epilogue: MFMA absorb (O @ out_absorb) -> ctx bf16.
// ---------------------------------------------------------------------------
__global__ __launch_bounds__(256, 4) void k3_attn(
    const ushort_t* __restrict__ Qbf, const ushort_t* __restrict__ Kbf,
    const ushort_t* __restrict__ VTbf, const float* __restrict__ oaT,
    ushort_t* __restrict__ ctxb)
{
    __shared__ __align__(16) ushort_t LDS[17920];
    ushort_t* Kt = LDS;                    // [64][136]
    ushort_t* Vt = LDS + 8704;             // [64][72]
    ushort_t* Pw = LDS + 8704 + 4608;      // [4][16][72]
    int j = threadIdx.x;
    int b = blockIdx.z, h = blockIdx.y, q0g = blockIdx.x * 64;
    int w = j >> 6, lane = j & 63;
    int tl = lane & 15, qd = lane >> 4;
    ushort_t* Pme = Pw + w * (16 * 72);

    bf8_t qfrag[4];
    {
        const ushort_t* qp = Qbf + ((size_t)((b * 8 + h) * 2048) + q0g + w * 16 + tl) * 128 + qd * 8;
#pragma unroll
        for (int ks = 0; ks < 4; ++ks) qfrag[ks] = *(const bf8_t*)(qp + ks * 32);
    }
    f4_t Oacc[4];
#pragma unroll
    for (int nt = 0; nt < 4; ++nt) Oacc[nt] = (f4_t){0.f, 0.f, 0.f, 0.f};
    float mrow[4] = {-1e30f, -1e30f, -1e30f, -1e30f};
    float lrow[4] = {0.f, 0.f, 0.f, 0.f};

    const size_t kbase = (size_t)b * 2048 * 128;
    const size_t vbase = (size_t)b * 64 * 2048;

    for (int it = 0; it < 32; ++it) {
        __syncthreads();
        {   // stage Kt (64 x 128 bf16)
            int r = j >> 2, c0 = (j & 3) * 32;
            const uint4* gp = (const uint4*)(Kbf + kbase + (size_t)(it * 64 + r) * 128 + c0);
            uint4 a0 = gp[0], a1 = gp[1], a2 = gp[2], a3 = gp[3];
            uint4* dp = (uint4*)(Kt + r * 136 + c0);
            dp[0] = a0; dp[1] = a1; dp[2] = a2; dp[3] = a3;
        }
        {   // stage Vt (64 d x 64 t bf16)
            int d = j >> 2, c0 = (j & 3) * 16;
            const uint4* gp = (const uint4*)(VTbf + vbase + (size_t)d * 2048 + it * 64 + c0);
            uint4 a0 = gp[0], a1 = gp[1];
            uint4* dp = (uint4*)(Vt + d * 72 + c0);
            dp[0] = a0; dp[1] = a1;
        }
        __syncthreads();
        f4_t S[4];
#pragma unroll
        for (int nt = 0; nt < 4; ++nt) {
            f4_t c = (f4_t){0.f, 0.f, 0.f, 0.f};
#pragma unroll
            for (int ks = 0; ks < 4; ++ks) {
                bf8_t kf = *(const bf8_t*)(Kt + (nt * 16 + tl) * 136 + ks * 32 + qd * 8);
                c = __builtin_amdgcn_mfma_f32_16x16x32_bf16(qfrag[ks], kf, c, 0, 0, 0);
            }
            S[nt] = c;
        }
        float mt[4], al[4], rsum[4];
#pragma unroll
        for (int r = 0; r < 4; ++r)
            mt[r] = fmaxf(fmaxf(S[0][r], S[1][r]), fmaxf(S[2][r], S[3][r]));
#pragma unroll
        for (int mask = 1; mask < 16; mask <<= 1)
#pragma unroll
            for (int r = 0; r < 4; ++r) mt[r] = fmaxf(mt[r], __shfl_xor(mt[r], mask));
#pragma unroll
        for (int r = 0; r < 4; ++r) {
            float mn = fmaxf(mrow[r], mt[r]);
            al[r] = __expf(mrow[r] - mn);
            mrow[r] = mn; rsum[r] = 0.f;
        }
#pragma unroll
        for (int nt = 0; nt < 4; ++nt)
#pragma unroll
            for (int r = 0; r < 4; ++r) {
                float p = __expf(S[nt][r] - mrow[r]);
                S[nt][r] = p; rsum[r] += p;
            }
#pragma unroll
        for (int mask = 1; mask < 16; mask <<= 1)
#pragma unroll
            for (int r = 0; r < 4; ++r) rsum[r] += __shfl_xor(rsum[r], mask);
#pragma unroll
        for (int r = 0; r < 4; ++r) lrow[r] = lrow[r] * al[r] + rsum[r];
#pragma unroll
        for (int nt = 0; nt < 4; ++nt)
#pragma unroll
            for (int r = 0; r < 4; ++r)
                Pme[(qd * 4 + r) * 72 + nt * 16 + tl] = f2bf(S[nt][r]);
#pragma unroll
        for (int nt = 0; nt < 4; ++nt)
#pragma unroll
            for (int r = 0; r < 4; ++r) Oacc[nt][r] *= al[r];
        __syncthreads();
        bf8_t pf[2];
#pragma unroll
        for (int ks = 0; ks < 2; ++ks) pf[ks] = *(const bf8_t*)(Pme + tl * 72 + ks * 32 + qd * 8);
#pragma unroll
        for (int nt = 0; nt < 4; ++nt)
#pragma unroll
            for (int ks = 0; ks < 2; ++ks) {
                bf8_t vf = *(const bf8_t*)(Vt + (nt * 16 + tl) * 72 + ks * 32 + qd * 8);
                Oacc[nt] = __builtin_amdgcn_mfma_f32_16x16x32_bf16(pf[ks], vf, Oacc[nt], 0, 0, 0);
            }
    }
    __syncthreads();
    {
        float invl[4];
#pragma unroll
        for (int r = 0; r < 4; ++r) invl[r] = 1.f / lrow[r];
#pragma unroll
        for (int nt = 0; nt < 4; ++nt)
#pragma unroll
            for (int r = 0; r < 4; ++r)
                Pme[(qd * 4 + r) * 72 + nt * 16 + tl] = f2bf(Oacc[nt][r] * invl[r]);
    }
    ushort_t* OA = LDS;  // [96][72]
    for (int e = j; e < 96 * 64; e += 256) {
        int v = e >> 6, r = e & 63;
        OA[v * 72 + r] = f2bf(oaT[h * 6144 + r * 96 + v]);
    }
    __syncthreads();
    {
        bf8_t of[2];
#pragma unroll
        for (int ks = 0; ks < 2; ++ks) of[ks] = *(const bf8_t*)(Pme + tl * 72 + ks * 32 + qd * 8);
#pragma unroll
        for (int nt = 0; nt < 6; ++nt) {
            f4_t c = (f4_t){0.f, 0.f, 0.f, 0.f};
#pragma unroll
            for (int ks = 0; ks < 2; ++ks) {
                bf8_t af = *(const bf8_t*)(OA + (nt * 16 + tl) * 72 + ks * 32 + qd * 8);
                c = __builtin_amdgcn_mfma_f32_16x16x32_bf16(of[ks], af, c, 0, 0, 0);
            }
#pragma unroll
            for (int r = 0; r < 4; ++r) {
                size_t tok = (size_t)(b * 2048 + q0g + w * 16 + qd * 4 + r);
                ctxb[tok * 768 + h * 96 + nt * 16 + tl] = f2bf(c[r]);
            }
        }
    }
}

// ---------------------------------------------------------------------------
// k5: MFMA wo-GEMM + fused residual + RMSNorm.
// grid 256 blocks x 32 tokens; full N=768/block (wave w owns cols w*192..).
// A = ctx bf16 staged in LDS (stride 776); B = wo bf16 straight from L2.
// ---------------------------------------------------------------------------
__global__ __launch_bounds__(256, 1) void k5_out(
    const void* __restrict__ src, const float* __restrict__ ws,
    const ushort_t* __restrict__ ctxb, void* __restrict__ out)
{
    const ushort_t* woB = (const ushort_t*)(ws + OFF_WOT);
    const float* nw = ws + OFF_NW;
    const int isbf = ((const int*)ws)[OFF_FLAG];
    __shared__ __align__(16) ushort_t ylds[32 * 776];   // A-tile, then y (49664 B)
    int j = threadIdx.x;
    int t0 = blockIdx.x * 32;
    int w = j >> 6, lane = j & 63;
    int tl = lane & 15, qd = lane >> 4;
    int n0 = w * 192;

    {   // stage A: ctx[t0..t0+31][0..767] bf16 -> LDS stride 776
        for (int e = j; e < 32 * 96; e += 256) {
            int row = e / 96, c16 = e - row * 96;
            uint4 v = *(const uint4*)(ctxb + (size_t)(t0 + row) * 768 + c16 * 8);
            *(uint4*)(ylds + row * 776 + c16 * 8) = v;
        }
    }
    __syncthreads();

    f4_t acc[2][12];
#pragma unroll
    for (int mt = 0; mt < 2; ++mt)
#pragma unroll
        for (int nt = 0; nt < 12; ++nt) acc[mt][nt] = (f4_t){0.f, 0.f, 0.f, 0.f};

#pragma unroll 2
    for (int ks = 0; ks < 24; ++ks) {
        bf8_t a0 = *(const bf8_t*)(ylds + tl * 776 + ks * 32 + qd * 8);
        bf8_t a1 = *(const bf8_t*)(ylds + (16 + tl) * 776 + ks * 32 + qd * 8);
#pragma unroll
        for (int nt = 0; nt < 12; ++nt) {
            bf8_t bfr = *(const bf8_t*)(woB + (size_t)(n0 + nt * 16 + tl) * 768 + ks * 32 + qd * 8);
            acc[0][nt] = __builtin_amdgcn_mfma_f32_16x16x32_bf16(a0, bfr, acc[0][nt], 0, 0, 0);
            acc[1][nt] = __builtin_amdgcn_mfma_f32_16x16x32_bf16(a1, bfr, acc[1][nt], 0, 0, 0);
        }
    }
    __syncthreads();   // all A-frag readers done; recycle ylds for y

    {   // y = attn_out + src (bf16, matching reference residual dtype)
#pragma unroll
        for (int mt = 0; mt < 2; ++mt)
#pragma unroll
            for (int nt = 0; nt < 12; ++nt)
#pragma unroll
                for (int r = 0; r < 4; ++r) {
                    int trow = mt * 16 + qd * 4 + r;
                    int col = n0 + nt * 16 + tl;
                    float yv = acc[mt][nt][r] + ldin(src, (size_t)(t0 + trow) * 768 + col, isbf);
                    ylds[trow * 776 + col] = f2bf(yv);
                }
    }
    __syncthreads();
    {   // rmsnorm rows: 8 lanes per token, 96 cols each
        int tt = j >> 3, sub = j & 7;
        const ushort_t* yp = ylds + tt * 776 + sub * 96;
        float ss = 0.f;
#pragma unroll
        for (int c = 0; c < 96; ++c) { float v = bf2f(yp[c]); ss += v * v; }
        ss += __shfl_xor(ss, 1); ss += __shfl_xor(ss, 2); ss += __shfl_xor(ss, 4);
        float rs = rsqrtf(ss * (1.f / 768.f) + EPSF);
        size_t base = (size_t)(t0 + tt) * 768 + sub * 96;
        if (isbf) {
            ushort_t* op = (ushort_t*)out + base;
#pragma unroll
            for (int c8 = 0; c8 < 12; ++c8) {
                ushort_t tmp[8];
#pragma unroll
                for (int c = 0; c < 8; ++c) {
                    float yv = bf2f(yp[c8 * 8 + c]);
                    float hv = bf2f(f2bf(yv * rs));    // .astype(bf16) before *w
                    tmp[c] = f2bf(hv * nw[sub * 96 + c8 * 8 + c]);
                }
                *(uint4*)(op + c8 * 8) = *(const uint4*)tmp;
            }
        } else {
            float* op = (float*)out + base;
#pragma unroll
            for (int c = 0; c < 96; ++c) {
                float yv = bf2f(yp[c]);
                op[c] = yv * rs * nw[sub * 96 + c];
            }
        }
    }
}

// ---------------------------------------------------------------------------
extern "C" void kernel_launch(void* const* d_in, const int* in_sizes, int n_in,
                              void* d_out, int out_size, void* d_ws, size_t ws_size,
                              hipStream_t stream)
{
    const void* src   = d_in[0];
    const void* wq_a  = d_in[1];
    const void* q_ln  = d_in[2];
    const void* wq_b  = d_in[3];
    const void* wkv_a = d_in[4];
    const void* kv_ln = d_in[5];
    const void* wkv_b = d_in[6];
    const void* wo    = d_in[7];
    const void* nw    = d_in[8];
    float* ws = (float*)d_ws;
    ushort_t* Kbf  = (ushort_t*)(ws + OFF_KBF);
    ushort_t* VTbf = (ushort_t*)(ws + OFF_VTB);
    ushort_t* Qbf  = (ushort_t*)(ws + OFF_QBF);
    ushort_t* ctxb = (ushort_t*)(ws + OFF_CTXF);

    det_k<<<dim3(1), dim3(1), 0, stream>>>((const unsigned int*)nw, (int*)ws + OFF_FLAG);
    prep_k<<<dim3(2304, 7), dim3(256), 0, stream>>>(wq_a, q_ln, wq_b, wkv_a, kv_ln, wkv_b, wo, nw, ws);
    k1_ckv<<<dim3(TOK / 32), dim3(256), 0, stream>>>(src, ws, Kbf, VTbf);
    k2_q<<<dim3(TOK / 8), dim3(256), 0, stream>>>(src, ws, Qbf);
    k3_attn<<<dim3(32, 8, 4), dim3(256), 0, stream>>>(Qbf, Kbf, VTbf, ws + OFF_OAT, ctxb);
    k5_out<<<dim3(TOK / 32), dim3(256), 0, stream>>>(src, ws, ctxb, d_out);
}

// Round 5
// 437.897 us; speedup vs baseline: 3.8370x; 1.1608x over previous
//
#include <hip/hip_runtime.h>

// ---------------------------------------------------------------------------
// MLA prefill (B=4, S=2048, D=768, H=8, q_rank=kv_rank=rope=64, nope=32, v=96)
// Round 5: k3 restructured (S^T scores -> cheap softmax, 2 barriers/tile,
// 8 waves/block); k1 at 512 threads for latency hiding. k5 MFMA (round 4).
// ---------------------------------------------------------------------------

#define DEV static __device__ __forceinline__
typedef unsigned short ushort_t;
typedef __attribute__((ext_vector_type(8))) short bf8_t;
typedef __attribute__((ext_vector_type(4))) float f4_t;

DEV float bf2f(unsigned int u) {
    union { float f; unsigned int i; } x; x.i = u << 16; return x.f;
}
DEV ushort_t f2bf(float f) {
    union { float f; unsigned int u; } x; x.f = f;
    unsigned int u = x.u;
    return (ushort_t)((u + 0x7fffu + ((u >> 16) & 1u)) >> 16);
}
DEV float ldin(const void* p, size_t i, int isbf) {
    return isbf ? bf2f(((const ushort_t*)p)[i]) : ((const float*)p)[i];
}

constexpr int   TOK   = 4 * 2048;                         // 8192 tokens
constexpr float EPSF  = 1e-6f;
constexpr float SCALE = 0.10206207261596575f;             // 96^-0.5
constexpr float L2_10000_OVER_32 = 0.4152410118609203f;   // log2(10000)/32

// workspace layout (float offsets)
constexpr size_t OFF_WOT   = 0;                 // wo bf16 [768][768] (row-major copy)
constexpr size_t OFF_WKVAT = 589824;            // wkv_aT [768][128] fp32
constexpr size_t OFF_WQAT  = 688128;            // wq_aT  [768][64] fp32
constexpr size_t OFF_WQBT  = 737280;            // wq_bT  [64][768] fp32
constexpr size_t OFF_QAF   = 786432;            // q_absorb [8][32][64] fp32
constexpr size_t OFF_OAT   = 802816;            // out_absorbT [8][r=64][v=96] fp32
constexpr size_t OFF_QLN   = 851968;
constexpr size_t OFF_KVLN  = 852032;
constexpr size_t OFF_NW    = 852096;
constexpr size_t OFF_FLAG  = 852864;
constexpr size_t OFF_CTXF  = 852880;            // ctx bf16 [8192][768] (ushort units)
constexpr size_t OFF_KBF   = 7144336;           // K' bf16 [4][2048][128]
constexpr size_t OFF_VTB   = 7668624;           // V^T bf16 [4][64][2048]
constexpr size_t OFF_QBF   = 7930768;           // Q' bf16 [4][8][2048][128]

// ---------------------------------------------------------------------------
__global__ void det_k(const unsigned int* __restrict__ nw_u, int* __restrict__ flag) {
    *flag = ((nw_u[0] & 0xffffu) != 0u) ? 1 : 0;
}

// ---------------------------------------------------------------------------
__global__ __launch_bounds__(256) void prep_k(
    const void* __restrict__ wq_a, const void* __restrict__ q_ln,
    const void* __restrict__ wq_b, const void* __restrict__ wkv_a,
    const void* __restrict__ kv_ln, const void* __restrict__ wkv_b,
    const void* __restrict__ wo, const void* __restrict__ nw,
    float* __restrict__ ws)
{
    const int isbf = ((const int*)ws)[OFF_FLAG];
    int i = blockIdx.x * 256 + threadIdx.x;
    int y = blockIdx.y;
    if (y == 0) {        // wo -> bf16 straight copy (row-major [o][k])
        if (i < 768 * 768) {
            ushort_t* wob = (ushort_t*)(ws + OFF_WOT);
            wob[i] = isbf ? ((const ushort_t*)wo)[i] : f2bf(((const float*)wo)[i]);
        }
    } else if (y == 1) {
        if (i < 768 * 128) { int k = i >> 7, o = i & 127; ws[OFF_WKVAT + i] = ldin(wkv_a, (size_t)o * 768 + k, isbf); }
    } else if (y == 2) {
        if (i < 768 * 64) { int k = i >> 6, o = i & 63; ws[OFF_WQAT + i] = ldin(wq_a, (size_t)o * 768 + k, isbf); }
    } else if (y == 3) {
        if (i < 64 * 768) { int k = i / 768, o = i - k * 768; ws[OFF_WQBT + i] = ldin(wq_b, (size_t)o * 64 + k, isbf); }
    } else if (y == 4) {
        if (i < 8 * 32 * 64) { int h = i >> 11; ws[OFF_QAF + i] = ldin(wkv_b, (size_t)h * 8192 + (i & 2047), isbf); }
    } else if (y == 5) { // out_absorbT [h][r][v] = wkv_b[h*128+32+v][r]
        if (i < 8 * 64 * 96) {
            int h = i / 6144, rem = i - h * 6144;
            int r = rem / 96, v = rem - r * 96;
            ws[OFF_OAT + i] = ldin(wkv_b, (size_t)h * 8192 + 2048 + v * 64 + r, isbf);
        }
    } else {
        if (i < 64)             ws[OFF_QLN + i]       = ldin(q_ln, i, isbf);
        else if (i < 128)       ws[OFF_KVLN + i - 64] = ldin(kv_ln, i - 64, isbf);
        else if (i < 128 + 768) ws[OFF_NW + i - 128]  = ldin(nw, i - 128, isbf);
    }
}

// ---------------------------------------------------------------------------
// k1: ckv = src @ wkv_a^T ; K'bf16[token][128] = [c_lat_n*w | rope(k_pe)],
//     VT bf16[b][64][2048]. 32 tokens/block, 512 threads (8 waves for latency).
// ---------------------------------------------------------------------------
__global__ __launch_bounds__(512) void k1_ckv(
    const void* __restrict__ src, const float* __restrict__ ws,
    ushort_t* __restrict__ Kbf, ushort_t* __restrict__ VTbf)
{
    const float* wkvaT = ws + OFF_WKVAT;
    const float* kvln  = ws + OFF_KVLN;
    const int isbf = ((const int*)ws)[OFF_FLAG];
    __shared__ float slds[32][68];
    __shared__ float ckv[32][132];
    int j = threadIdx.x;
    int t0 = blockIdx.x * 32;
    int o = j & 127, tg = j >> 7;   // tg 0..3, each handles 8 tokens
    float acc[8];
#pragma unroll
    for (int i = 0; i < 8; ++i) acc[i] = 0.f;

    for (int k0 = 0; k0 < 768; k0 += 64) {
        {   // stage 32x64 chunk of src into LDS (512 thr x 4 elems)
            int tt = j >> 4, kk = (j & 15) * 4;
            size_t off = (size_t)(t0 + tt) * 768 + k0 + kk;
            float* d = &slds[tt][kk];
            if (isbf) {
                uint2 u = *(const uint2*)((const ushort_t*)src + off);
                d[0] = bf2f(u.x & 0xffff); d[1] = bf2f(u.x >> 16);
                d[2] = bf2f(u.y & 0xffff); d[3] = bf2f(u.y >> 16);
            } else {
                *(float4*)d = *(const float4*)((const float*)src + off);
            }
        }
        __syncthreads();
#pragma unroll 1
        for (int kk = 0; kk < 64; kk += 4) {
            float w0 = wkvaT[(k0 + kk) * 128 + o];
            float w1 = wkvaT[(k0 + kk + 1) * 128 + o];
            float w2 = wkvaT[(k0 + kk + 2) * 128 + o];
            float w3 = wkvaT[(k0 + kk + 3) * 128 + o];
#pragma unroll
            for (int i = 0; i < 8; ++i) {
                float4 s4 = *(const float4*)&slds[tg * 8 + i][kk];
                acc[i] += s4.x * w0 + s4.y * w1 + s4.z * w2 + s4.w * w3;
            }
        }
        __syncthreads();
    }
#pragma unroll
    for (int i = 0; i < 8; ++i) ckv[tg * 8 + i][o] = acc[i];
    __syncthreads();

    if (j < 256) {
        int tt = j >> 3, l = j & 7;
        float ss = 0.f;
#pragma unroll
        for (int i = 0; i < 8; ++i) { float v = ckv[tt][l * 8 + i]; ss += v * v; }
        ss += __shfl_xor(ss, 1); ss += __shfl_xor(ss, 2); ss += __shfl_xor(ss, 4);
        float rs = rsqrtf(ss * (1.f / 64.f) + EPSF);
        size_t base = (size_t)(t0 + tt) * 128;
        ushort_t kb[8];
        float clw[8];
#pragma unroll
        for (int i = 0; i < 8; ++i) {
            int o2 = l * 8 + i;
            float cl = ckv[tt][o2] * rs;
            if (isbf) cl = bf2f(f2bf(cl));   // reference: .astype(bf16) before *w
            clw[i] = cl * kvln[o2];
            kb[i] = f2bf(clw[i]);
        }
        uint4 pack;
        pack.x = kb[0] | ((unsigned)kb[1] << 16); pack.y = kb[2] | ((unsigned)kb[3] << 16);
        pack.z = kb[4] | ((unsigned)kb[5] << 16); pack.w = kb[6] | ((unsigned)kb[7] << 16);
        *(uint4*)&Kbf[base + l * 8] = pack;
        int pos = (t0 + tt) & 2047;
        ushort_t r0[4], r1[4];
#pragma unroll
        for (int i = 0; i < 4; ++i) {
            int p = l * 4 + i;
            float inv = exp2f(-(float)p * L2_10000_OVER_32);
            float ang = (float)pos * inv;
            float sn = sinf(ang), cs = cosf(ang);
            float e = ckv[tt][64 + 2 * p], od = ckv[tt][64 + 2 * p + 1];
            r0[i] = f2bf(e * cs - od * sn);
            r1[i] = f2bf(od * cs + e * sn);
        }
        uint2 p0, p1;
        p0.x = r0[0] | ((unsigned)r0[1] << 16); p0.y = r0[2] | ((unsigned)r0[3] << 16);
        p1.x = r1[0] | ((unsigned)r1[1] << 16); p1.y = r1[2] | ((unsigned)r1[3] << 16);
        *(uint2*)&Kbf[base + 64 + l * 4] = p0;
        *(uint2*)&Kbf[base + 96 + l * 4] = p1;
#pragma unroll
        for (int i = 0; i < 8; ++i) ckv[tt][l * 8 + i] = clw[i];
    }
    __syncthreads();
    if (j < 256) {   // VT[b][r][t] = c_lat_n[t][r]
        int t = j & 31, rb = (j >> 5) * 8;
        int bb = t0 >> 11, col = (t0 & 2047) + t;
#pragma unroll
        for (int i = 0; i < 8; ++i) {
            int r = rb + i;
            VTbf[((size_t)(bb * 64 + r)) * 2048 + col] = f2bf(ckv[t][r]);
        }
    }
}

// ---------------------------------------------------------------------------
// k2: q = rmsnorm(src@wq_a^T)@wq_b^T ; per head: q_lat = q_nope@q_absorb,
//     q_pe = rope(q_pe). Store Q' bf16 [b][h][2048][128] * SCALE.
// ---------------------------------------------------------------------------
__global__ __launch_bounds__(256) void k2_q(
    const void* __restrict__ src, const float* __restrict__ ws, ushort_t* __restrict__ Qbf)
{
    const float* wqaT = ws + OFF_WQAT;
    const float* wqbT = ws + OFF_WQBT;
    const float* qaF  = ws + OFF_QAF;
    const float* qln  = ws + OFF_QLN;
    const int isbf = ((const int*)ws)[OFF_FLAG];
    __shared__ float slds[8][68];
    __shared__ float tlds[8][68];
    __shared__ float qlds[8][768];
    int j = threadIdx.x;
    int t0 = blockIdx.x * 8;

    {
        int o = j & 63, tg = j >> 6;
        float a0 = 0.f, a1 = 0.f;
        for (int k0 = 0; k0 < 768; k0 += 64) {
            {
                int tt = j >> 5, kk = (j & 31) * 2;
                size_t off = (size_t)(t0 + tt) * 768 + k0 + kk;
                if (isbf) {
                    unsigned int u = *(const unsigned int*)((const ushort_t*)src + off);
                    slds[tt][kk] = bf2f(u & 0xffff); slds[tt][kk + 1] = bf2f(u >> 16);
                } else {
                    const float* p = (const float*)src + off;
                    slds[tt][kk] = p[0]; slds[tt][kk + 1] = p[1];
                }
            }
            __syncthreads();
#pragma unroll 1
            for (int kk = 0; kk < 64; kk += 4) {
                float w0 = wqaT[(k0 + kk) * 64 + o], w1 = wqaT[(k0 + kk + 1) * 64 + o];
                float w2 = wqaT[(k0 + kk + 2) * 64 + o], w3 = wqaT[(k0 + kk + 3) * 64 + o];
                float4 s0 = *(const float4*)&slds[tg * 2][kk];
                float4 s1 = *(const float4*)&slds[tg * 2 + 1][kk];
                a0 += s0.x * w0 + s0.y * w1 + s0.z * w2 + s0.w * w3;
                a1 += s1.x * w0 + s1.y * w1 + s1.z * w2 + s1.w * w3;
            }
            __syncthreads();
        }
        tlds[tg * 2][o] = a0; tlds[tg * 2 + 1][o] = a1;
    }
    __syncthreads();
    {
        int tt = j >> 5, l = j & 31;
        float v0 = tlds[tt][l * 2], v1 = tlds[tt][l * 2 + 1];
        float ss = v0 * v0 + v1 * v1;
        ss += __shfl_xor(ss, 1); ss += __shfl_xor(ss, 2); ss += __shfl_xor(ss, 4);
        ss += __shfl_xor(ss, 8); ss += __shfl_xor(ss, 16);
        float rs = rsqrtf(ss * (1.f / 64.f) + EPSF);
        float n0 = v0 * rs, n1 = v1 * rs;
        if (isbf) { n0 = bf2f(f2bf(n0)); n1 = bf2f(f2bf(n1)); }
        tlds[tt][l * 2]     = n0 * qln[l * 2];
        tlds[tt][l * 2 + 1] = n1 * qln[l * 2 + 1];
    }
    __syncthreads();
    {
        float qa[8][3];
#pragma unroll
        for (int i = 0; i < 8; ++i) { qa[i][0] = 0.f; qa[i][1] = 0.f; qa[i][2] = 0.f; }
#pragma unroll 1
        for (int k = 0; k < 64; k += 4) {
            float w[4][3];
#pragma unroll
            for (int kk = 0; kk < 4; ++kk) {
                const float* wp = wqbT + (size_t)(k + kk) * 768 + j;
                w[kk][0] = wp[0]; w[kk][1] = wp[256]; w[kk][2] = wp[512];
            }
#pragma unroll
            for (int i = 0; i < 8; ++i) {
                float4 t4 = *(const float4*)&tlds[i][k];
                qa[i][0] += t4.x * w[0][0] + t4.y * w[1][0] + t4.z * w[2][0] + t4.w * w[3][0];
                qa[i][1] += t4.x * w[0][1] + t4.y * w[1][1] + t4.z * w[2][1] + t4.w * w[3][1];
                qa[i][2] += t4.x * w[0][2] + t4.y * w[1][2] + t4.z * w[2][2] + t4.w * w[3][2];
            }
        }
#pragma unroll
        for (int i = 0; i < 8; ++i) {
            qlds[i][j] = qa[i][0]; qlds[i][j + 256] = qa[i][1]; qlds[i][j + 512] = qa[i][2];
        }
    }
    __syncthreads();
    {
        int wv = j >> 6, lane = j & 63;
        for (int u = wv * 16; u < wv * 16 + 16; ++u) {
            int tt = u >> 3, h = u & 7;
            int qb = h * 96;
            float acc = 0.f;
#pragma unroll 4
            for (int d = 0; d < 32; ++d) acc += qlds[tt][qb + d] * qaF[(h * 32 + d) * 64 + lane];
            int token = t0 + tt, pos = token & 2047;
            size_t qoff = ((size_t)((token >> 11) * 8 + h) * 2048 + pos) * 128;
            Qbf[qoff + lane] = f2bf(acc * SCALE);
            if (lane < 32) {
                int p = lane;
                float e = qlds[tt][qb + 32 + 2 * p], od = qlds[tt][qb + 32 + 2 * p + 1];
                float inv = exp2f(-(float)p * L2_10000_OVER_32);
                float ang = (float)pos * inv;
                float sn = sinf(ang), cs = cosf(ang);
                Qbf[qoff + 64 + p] = f2bf((e * cs - od * sn) * SCALE);
                Qbf[qoff + 96 + p] = f2bf((od * cs + e * sn) * SCALE);
            }
        }
    }
}

// ---------------------------------------------------------------------------
// k3: MFMA flash attention v2. grid (16,8,4): 128 q/block, 8 waves (16 q/wave),
// K-tiles of 64. Scores computed as S^T = K·Q^T so each lane owns ONE q:
// softmax = in-lane reduce + 2 shfl_xor; P packed to LDS via b64 writes.
// 2 barriers/tile. LDS: Kt[64][136] | Vt[64][72] | P [8 waves][16][72].
// ---------------------------------------------------------------------------
__global__ __launch_bounds__(512, 4) void k3_attn(
    const ushort_t* __restrict__ Qbf, const ushort_t* __restrict__ Kbf,
    const ushort_t* __restrict__ VTbf, const float* __restrict__ oaT,
    ushort_t* __restrict__ ctxb)
{
    __shared__ __align__(16) ushort_t LDS[22528];   // 45056 B
    ushort_t* Kt = LDS;                    // [64][136]
    ushort_t* Vt = LDS + 8704;             // [64][72]
    ushort_t* Pw = LDS + 13312;            // [8][16][72]
    int j = threadIdx.x;
    int b = blockIdx.z, h = blockIdx.y, q0g = blockIdx.x * 128;
    int w = j >> 6, lane = j & 63;
    int tl = lane & 15, qd = lane >> 4;
    ushort_t* Pme = Pw + w * 1152;
    int qw = q0g + w * 16;                 // wave's q base

    // Q fragment (B operand): lane holds Q[n=q=qw+tl][k=ks*32+qd*8+0..7]
    bf8_t qfrag[4];
    {
        const ushort_t* qp = Qbf + ((size_t)((b * 8 + h) * 2048) + qw + tl) * 128 + qd * 8;
#pragma unroll
        for (int ks = 0; ks < 4; ++ks) qfrag[ks] = *(const bf8_t*)(qp + ks * 32);
    }
    f4_t Oacc[4];   // O[q=qd*4+r][d=nt*16+tl]
#pragma unroll
    for (int nt = 0; nt < 4; ++nt) Oacc[nt] = (f4_t){0.f, 0.f, 0.f, 0.f};
    float m_own = -1e30f, l_own = 0.f;     // softmax state for q = qw+tl

    const size_t kbase = (size_t)b * 2048 * 128;
    const size_t vbase = (size_t)b * 64 * 2048;

    for (int it = 0; it < 32; ++it) {
        __syncthreads();   // everyone done reading Kt/Vt of previous tile
        {   // stage Kt (64 t x 128 d bf16): 512 thr x 32 B
            int r = j >> 3, c0 = (j & 7) * 16;
            const uint4* gp = (const uint4*)(Kbf + kbase + (size_t)(it * 64 + r) * 128 + c0);
            uint4 a0 = gp[0], a1 = gp[1];
            uint4* dp = (uint4*)(Kt + r * 136 + c0);
            dp[0] = a0; dp[1] = a1;
        }
        {   // stage Vt (64 d x 64 t bf16): 512 thr x 16 B
            int d = j >> 3, c0 = (j & 7) * 8;
            uint4 v = *(const uint4*)(VTbf + vbase + (size_t)d * 2048 + it * 64 + c0);
            *(uint4*)(Vt + d * 72 + c0) = v;
        }
        __syncthreads();
        // scores S^T: C[m=t][n=q]; lane holds q=tl, t = nt*16 + qd*4 + r
        f4_t S[4];
#pragma unroll
        for (int nt = 0; nt < 4; ++nt) {
            f4_t c = (f4_t){0.f, 0.f, 0.f, 0.f};
#pragma unroll
            for (int ks = 0; ks < 4; ++ks) {
                bf8_t kf = *(const bf8_t*)(Kt + (nt * 16 + tl) * 136 + ks * 32 + qd * 8);
                c = __builtin_amdgcn_mfma_f32_16x16x32_bf16(kf, qfrag[ks], c, 0, 0, 0);
            }
            S[nt] = c;
        }
        // online softmax for q=tl: 16 in-lane + 2 shfl_xor (across qd groups)
        float mt;
        {
            float a0 = fmaxf(fmaxf(S[0][0], S[0][1]), fmaxf(S[0][2], S[0][3]));
            float a1 = fmaxf(fmaxf(S[1][0], S[1][1]), fmaxf(S[1][2], S[1][3]));
            float a2 = fmaxf(fmaxf(S[2][0], S[2][1]), fmaxf(S[2][2], S[2][3]));
            float a3 = fmaxf(fmaxf(S[3][0], S[3][1]), fmaxf(S[3][2], S[3][3]));
            mt = fmaxf(fmaxf(a0, a1), fmaxf(a2, a3));
        }
        mt = fmaxf(mt, __shfl_xor(mt, 16));
        mt = fmaxf(mt, __shfl_xor(mt, 32));
        float mn = fmaxf(m_own, mt);
        float al = __expf(m_own - mn);
        float rsum = 0.f;
#pragma unroll
        for (int nt = 0; nt < 4; ++nt)
#pragma unroll
            for (int r = 0; r < 4; ++r) {
                float p = __expf(S[nt][r] - mn);
                S[nt][r] = p; rsum += p;
            }
        rsum += __shfl_xor(rsum, 16);
        rsum += __shfl_xor(rsum, 32);
        l_own = l_own * al + rsum;
        m_own = mn;
        // P[q=tl][t] -> LDS, 4 packed b64 writes (t = nt*16 + qd*4 + 0..3)
#pragma unroll
        for (int nt = 0; nt < 4; ++nt) {
            uint2 pk;
            pk.x = f2bf(S[nt][0]) | ((unsigned)f2bf(S[nt][1]) << 16);
            pk.y = f2bf(S[nt][2]) | ((unsigned)f2bf(S[nt][3]) << 16);
            *(uint2*)(Pme + tl * 72 + nt * 16 + qd * 4) = pk;
        }
        // O rescale: alpha for rows q = qd*4+r via intra-group broadcast
#pragma unroll
        for (int r = 0; r < 4; ++r) {
            float alr = __shfl(al, (lane & 48) + qd * 4 + r);
#pragma unroll
            for (int nt = 0; nt < 4; ++nt) Oacc[nt][r] *= alr;
        }
        // PV (no barrier: Pme is per-wave): A=P[m=q], B=V^T[n=d]
        bf8_t pf[2];
#pragma unroll
        for (int ks = 0; ks < 2; ++ks) pf[ks] = *(const bf8_t*)(Pme + tl * 72 + ks * 32 + qd * 8);
#pragma unroll
        for (int nt = 0; nt < 4; ++nt)
#pragma unroll
            for (int ks = 0; ks < 2; ++ks) {
                bf8_t vf = *(const bf8_t*)(Vt + (nt * 16 + tl) * 72 + ks * 32 + qd * 8);
                Oacc[nt] = __builtin_amdgcn_mfma_f32_16x16x32_bf16(pf[ks], vf, Oacc[nt], 0, 0, 0);
            }
    }
    // normalize O into Pme ([q][d64] layout) with broadcast 1/l
    {
        float linv[4];
#pragma unroll
        for (int r = 0; r < 4; ++r) {
            float lq = __shfl(l_own, (lane & 48) + qd * 4 + r);
            linv[r] = 1.f / lq;
        }
#pragma unroll
        for (int nt = 0; nt < 4; ++nt)
#pragma unroll
            for (int r = 0; r < 4; ++r)
                Pme[(qd * 4 + r) * 72 + nt * 16 + tl] = f2bf(Oacc[nt][r] * linv[r]);
    }
    __syncthreads();   // all waves done with Kt/Vt; recycle Kt area for OA
    ushort_t* OA = LDS;  // [96][72]
    for (int e = j; e < 96 * 64; e += 512) {
        int v = e >> 6, r = e & 63;
        OA[v * 72 + r] = f2bf(oaT[h * 6144 + r * 96 + v]);
    }
    __syncthreads();
    {   // ctx[q][v] = sum_r O[q][r] * oa[r][v]
        bf8_t of[2];
#pragma unroll
        for (int ks = 0; ks < 2; ++ks) of[ks] = *(const bf8_t*)(Pme + tl * 72 + ks * 32 + qd * 8);
#pragma unroll
        for (int nt = 0; nt < 6; ++nt) {
            f4_t c = (f4_t){0.f, 0.f, 0.f, 0.f};
#pragma unroll
            for (int ks = 0; ks < 2; ++ks) {
                bf8_t af = *(const bf8_t*)(OA + (nt * 16 + tl) * 72 + ks * 32 + qd * 8);
                c = __builtin_amdgcn_mfma_f32_16x16x32_bf16(of[ks], af, c, 0, 0, 0);
            }
#pragma unroll
            for (int r = 0; r < 4; ++r) {
                size_t tok = (size_t)(b * 2048 + qw + qd * 4 + r);
                ctxb[tok * 768 + h * 96 + nt * 16 + tl] = f2bf(c[r]);
            }
        }
    }
}

// ---------------------------------------------------------------------------
// k5: MFMA wo-GEMM + fused residual + RMSNorm. 256 blocks x 32 tokens.
// ---------------------------------------------------------------------------
__global__ __launch_bounds__(256, 1) void k5_out(
    const void* __restrict__ src, const float* __restrict__ ws,
    const ushort_t* __restrict__ ctxb, void* __restrict__ out)
{
    const ushort_t* woB = (const ushort_t*)(ws + OFF_WOT);
    const float* nw = ws + OFF_NW;
    const int isbf = ((const int*)ws)[OFF_FLAG];
    __shared__ __align__(16) ushort_t ylds[32 * 776];
    int j = threadIdx.x;
    int t0 = blockIdx.x * 32;
    int w = j >> 6, lane = j & 63;
    int tl = lane & 15, qd = lane >> 4;
    int n0 = w * 192;

    {   // stage A: ctx[t0..t0+31][0..767] bf16 -> LDS stride 776
        for (int e = j; e < 32 * 96; e += 256) {
            int row = e / 96, c16 = e - row * 96;
            uint4 v = *(const uint4*)(ctxb + (size_t)(t0 + row) * 768 + c16 * 8);
            *(uint4*)(ylds + row * 776 + c16 * 8) = v;
        }
    }
    __syncthreads();

    f4_t acc[2][12];
#pragma unroll
    for (int mt = 0; mt < 2; ++mt)
#pragma unroll
        for (int nt = 0; nt < 12; ++nt) acc[mt][nt] = (f4_t){0.f, 0.f, 0.f, 0.f};

#pragma unroll 2
    for (int ks = 0; ks < 24; ++ks) {
        bf8_t a0 = *(const bf8_t*)(ylds + tl * 776 + ks * 32 + qd * 8);
        bf8_t a1 = *(const bf8_t*)(ylds + (16 + tl) * 776 + ks * 32 + qd * 8);
#pragma unroll
        for (int nt = 0; nt < 12; ++nt) {
            bf8_t bfr = *(const bf8_t*)(woB + (size_t)(n0 + nt * 16 + tl) * 768 + ks * 32 + qd * 8);
            acc[0][nt] = __builtin_amdgcn_mfma_f32_16x16x32_bf16(a0, bfr, acc[0][nt], 0, 0, 0);
            acc[1][nt] = __builtin_amdgcn_mfma_f32_16x16x32_bf16(a1, bfr, acc[1][nt], 0, 0, 0);
        }
    }
    __syncthreads();   // recycle ylds for y

    {   // y = attn_out + src (bf16, matching reference residual dtype)
#pragma unroll
        for (int mt = 0; mt < 2; ++mt)
#pragma unroll
            for (int nt = 0; nt < 12; ++nt)
#pragma unroll
                for (int r = 0; r < 4; ++r) {
                    int trow = mt * 16 + qd * 4 + r;
                    int col = n0 + nt * 16 + tl;
                    float yv = acc[mt][nt][r] + ldin(src, (size_t)(t0 + trow) * 768 + col, isbf);
                    ylds[trow * 776 + col] = f2bf(yv);
                }
    }
    __syncthreads();
    {   // rmsnorm rows: 8 lanes per token, 96 cols each
        int tt = j >> 3, sub = j & 7;
        const ushort_t* yp = ylds + tt * 776 + sub * 96;
        float ss = 0.f;
#pragma unroll
        for (int c = 0; c < 96; ++c) { float v = bf2f(yp[c]); ss += v * v; }
        ss += __shfl_xor(ss, 1); ss += __shfl_xor(ss, 2); ss += __shfl_xor(ss, 4);
        float rs = rsqrtf(ss * (1.f / 768.f) + EPSF);
        size_t base = (size_t)(t0 + tt) * 768 + sub * 96;
        if (isbf) {
            ushort_t* op = (ushort_t*)out + base;
#pragma unroll
            for (int c8 = 0; c8 < 12; ++c8) {
                ushort_t tmp[8];
#pragma unroll
                for (int c = 0; c < 8; ++c) {
                    float yv = bf2f(yp[c8 * 8 + c]);
                    float hv = bf2f(f2bf(yv * rs));    // .astype(bf16) before *w
                    tmp[c] = f2bf(hv * nw[sub * 96 + c8 * 8 + c]);
                }
                *(uint4*)(op + c8 * 8) = *(const uint4*)tmp;
            }
        } else {
            float* op = (float*)out + base;
#pragma unroll
            for (int c = 0; c < 96; ++c) {
                float yv = bf2f(yp[c]);
                op[c] = yv * rs * nw[sub * 96 + c];
            }
        }
    }
}

// ---------------------------------------------------------------------------
extern "C" void kernel_launch(void* const* d_in, const int* in_sizes, int n_in,
                              void* d_out, int out_size, void* d_ws, size_t ws_size,
                              hipStream_t stream)
{
    const void* src   = d_in[0];
    const void* wq_a  = d_in[1];
    const void* q_ln  = d_in[2];
    const void* wq_b  = d_in[3];
    const void* wkv_a = d_in[4];
    const void* kv_ln = d_in[5];
    const void* wkv_b = d_in[6];
    const void* wo    = d_in[7];
    const void* nw    = d_in[8];
    float* ws = (float*)d_ws;
    ushort_t* Kbf  = (ushort_t*)(ws + OFF_KBF);
    ushort_t* VTbf = (ushort_t*)(ws + OFF_VTB);
    ushort_t* Qbf  = (ushort_t*)(ws + OFF_QBF);
    ushort_t* ctxb = (ushort_t*)(ws + OFF_CTXF);

    det_k<<<dim3(1), dim3(1), 0, stream>>>((const unsigned int*)nw, (int*)ws + OFF_FLAG);
    prep_k<<<dim3(2304, 7), dim3(256), 0, stream>>>(wq_a, q_ln, wq_b, wkv_a, kv_ln, wkv_b, wo, nw, ws);
    k1_ckv<<<dim3(TOK / 32), dim3(512), 0, stream>>>(src, ws, Kbf, VTbf);
    k2_q<<<dim3(TOK / 8), dim3(256), 0, stream>>>(src, ws, Qbf);
    k3_attn<<<dim3(16, 8, 4), dim3(512), 0, stream>>>(Qbf, Kbf, VTbf, ws + OFF_OAT, ctxb);
    k5_out<<<dim3(TOK / 32), dim3(256), 0, stream>>>(src, ws, ctxb, d_out);
}

// Round 6
// 385.233 us; speedup vs baseline: 4.3615x; 1.1367x over previous
//
#include <hip/hip_runtime.h>

// ---------------------------------------------------------------------------
// MLA prefill (B=4, S=2048, D=768, H=8, q_rank=kv_rank=rope=64, nope=32, v=96)
// Round 6: k2 rewritten as barrier-free per-wave MFMA chain + RoPE table.
// k3 (flash attn) and k5 (wo GEMM) unchanged from round 5.
// ---------------------------------------------------------------------------

#define DEV static __device__ __forceinline__
typedef unsigned short ushort_t;
typedef __attribute__((ext_vector_type(8))) short bf8_t;
typedef __attribute__((ext_vector_type(4))) float f4_t;

DEV float bf2f(unsigned int u) {
    union { float f; unsigned int i; } x; x.i = u << 16; return x.f;
}
DEV ushort_t f2bf(float f) {
    union { float f; unsigned int u; } x; x.f = f;
    unsigned int u = x.u;
    return (ushort_t)((u + 0x7fffu + ((u >> 16) & 1u)) >> 16);
}
DEV float ldin(const void* p, size_t i, int isbf) {
    return isbf ? bf2f(((const ushort_t*)p)[i]) : ((const float*)p)[i];
}

constexpr int   TOK   = 4 * 2048;                         // 8192 tokens
constexpr float EPSF  = 1e-6f;
constexpr float SCALE = 0.10206207261596575f;             // 96^-0.5
constexpr float L2_10000_OVER_32 = 0.4152410118609203f;   // log2(10000)/32

// workspace layout (float offsets)
constexpr size_t OFF_WOT   = 0;                 // wo bf16 [768][768]
constexpr size_t OFF_WKVAT = 589824;            // wkv_aT [768][128] fp32 (k1)
constexpr size_t OFF_WQAT  = 688128;            // wq_a bf16 [64][768] (k2 GEMM1 B)
constexpr size_t OFF_WQBT  = 737280;            // wq_b bf16 [768][64] (k2 GEMM2 B)
constexpr size_t OFF_QAF   = 786432;            // q_absorbT*SCALE bf16 [8][64][32]
constexpr size_t OFF_OAT   = 802816;            // out_absorbT [8][64][96] fp32
constexpr size_t OFF_QLN   = 851968;
constexpr size_t OFF_KVLN  = 852032;
constexpr size_t OFF_NW    = 852096;
constexpr size_t OFF_FLAG  = 852864;
constexpr size_t OFF_CTXF  = 852880;            // ctx bf16 [8192][768] (ushort units)
constexpr size_t OFF_SRCBF = 3998608;           // src bf16 copy (fp32 mode only)
constexpr size_t OFF_KBF   = 7144336;           // K' bf16 [4][2048][128]
constexpr size_t OFF_VTB   = 7668624;           // V^T bf16 [4][64][2048]
constexpr size_t OFF_QBF   = 7930768;           // Q' bf16 [4][8][2048][128]
constexpr size_t OFF_ROPE  = 12125072;          // rope table float2 [2048][32]

// ---------------------------------------------------------------------------
__global__ void det_k(const unsigned int* __restrict__ nw_u, int* __restrict__ flag) {
    *flag = ((nw_u[0] & 0xffffu) != 0u) ? 1 : 0;
}

// ---------------------------------------------------------------------------
__global__ __launch_bounds__(256) void prep_k(
    const void* __restrict__ wq_a, const void* __restrict__ q_ln,
    const void* __restrict__ wq_b, const void* __restrict__ wkv_a,
    const void* __restrict__ kv_ln, const void* __restrict__ wkv_b,
    const void* __restrict__ wo, const void* __restrict__ nw,
    float* __restrict__ ws)
{
    const int isbf = ((const int*)ws)[OFF_FLAG];
    int i = blockIdx.x * 256 + threadIdx.x;
    int y = blockIdx.y;
    if (y == 0) {        // wo -> bf16 straight copy
        if (i < 768 * 768) {
            ushort_t* wob = (ushort_t*)(ws + OFF_WOT);
            wob[i] = isbf ? ((const ushort_t*)wo)[i] : f2bf(((const float*)wo)[i]);
        }
    } else if (y == 1) { // wkv_aT fp32 (k1)
        if (i < 768 * 128) { int k = i >> 7, o = i & 127; ws[OFF_WKVAT + i] = ldin(wkv_a, (size_t)o * 768 + k, isbf); }
    } else if (y == 2) { // wq_a bf16 straight [64][768]
        if (i < 64 * 768) {
            ushort_t* d = (ushort_t*)(ws + OFF_WQAT);
            d[i] = isbf ? ((const ushort_t*)wq_a)[i] : f2bf(((const float*)wq_a)[i]);
        }
    } else if (y == 3) { // wq_b bf16 straight [768][64]
        if (i < 768 * 64) {
            ushort_t* d = (ushort_t*)(ws + OFF_WQBT);
            d[i] = isbf ? ((const ushort_t*)wq_b)[i] : f2bf(((const float*)wq_b)[i]);
        }
    } else if (y == 4) { // q_absorbT * SCALE bf16 [8][r=64][d=32]
        if (i < 8 * 64 * 32) {
            int h = i >> 11, rem = i & 2047, r = rem >> 5, d = rem & 31;
            ushort_t* dst = (ushort_t*)(ws + OFF_QAF);
            dst[i] = f2bf(ldin(wkv_b, (size_t)(h * 128 + d) * 64 + r, isbf) * SCALE);
        }
    } else if (y == 5) { // out_absorbT [h][r][v] fp32
        if (i < 8 * 64 * 96) {
            int h = i / 6144, rem = i - h * 6144;
            int r = rem / 96, v = rem - r * 96;
            ws[OFF_OAT + i] = ldin(wkv_b, (size_t)h * 8192 + 2048 + v * 64 + r, isbf);
        }
    } else if (y == 6) { // norm vectors
        if (i < 64)             ws[OFF_QLN + i]       = ldin(q_ln, i, isbf);
        else if (i < 128)       ws[OFF_KVLN + i - 64] = ldin(kv_ln, i - 64, isbf);
        else if (i < 128 + 768) ws[OFF_NW + i - 128]  = ldin(nw, i - 128, isbf);
    } else {             // rope table [pos][p] = (cos, sin)
        if (i < 2048 * 32) {
            int pos = i >> 5, p = i & 31;
            float inv = exp2f(-(float)p * L2_10000_OVER_32);
            float ang = (float)pos * inv;
            float2* tab = (float2*)(ws + OFF_ROPE);
            tab[i] = make_float2(cosf(ang), sinf(ang));
        }
    }
}

// ---------------------------------------------------------------------------
// k1: ckv = src @ wkv_a^T ; K'bf16[token][128] = [c_lat_n*w | rope(k_pe)],
//     VT bf16[b][64][2048]. 32 tokens/block, 512 threads. Emits src bf16 copy
//     in fp32 mode (for k2's direct MFMA A-frag loads).
// ---------------------------------------------------------------------------
__global__ __launch_bounds__(512) void k1_ckv(
    const void* __restrict__ src, const float* __restrict__ ws,
    ushort_t* __restrict__ Kbf, ushort_t* __restrict__ VTbf,
    ushort_t* __restrict__ srcbf)
{
    const float* wkvaT = ws + OFF_WKVAT;
    const float* kvln  = ws + OFF_KVLN;
    const float2* tab  = (const float2*)(ws + OFF_ROPE);
    const int isbf = ((const int*)ws)[OFF_FLAG];
    __shared__ float slds[32][68];
    __shared__ float ckv[32][132];
    int j = threadIdx.x;
    int t0 = blockIdx.x * 32;
    int o = j & 127, tg = j >> 7;
    float acc[8];
#pragma unroll
    for (int i = 0; i < 8; ++i) acc[i] = 0.f;

    for (int k0 = 0; k0 < 768; k0 += 64) {
        {
            int tt = j >> 4, kk = (j & 15) * 4;
            size_t off = (size_t)(t0 + tt) * 768 + k0 + kk;
            float* d = &slds[tt][kk];
            if (isbf) {
                uint2 u = *(const uint2*)((const ushort_t*)src + off);
                d[0] = bf2f(u.x & 0xffff); d[1] = bf2f(u.x >> 16);
                d[2] = bf2f(u.y & 0xffff); d[3] = bf2f(u.y >> 16);
            } else {
                float4 f = *(const float4*)((const float*)src + off);
                *(float4*)d = f;
                ushort_t tmp[4] = {f2bf(f.x), f2bf(f.y), f2bf(f.z), f2bf(f.w)};
                *(uint2*)(srcbf + off) = *(const uint2*)tmp;
            }
        }
        __syncthreads();
#pragma unroll 1
        for (int kk = 0; kk < 64; kk += 4) {
            float w0 = wkvaT[(k0 + kk) * 128 + o];
            float w1 = wkvaT[(k0 + kk + 1) * 128 + o];
            float w2 = wkvaT[(k0 + kk + 2) * 128 + o];
            float w3 = wkvaT[(k0 + kk + 3) * 128 + o];
#pragma unroll
            for (int i = 0; i < 8; ++i) {
                float4 s4 = *(const float4*)&slds[tg * 8 + i][kk];
                acc[i] += s4.x * w0 + s4.y * w1 + s4.z * w2 + s4.w * w3;
            }
        }
        __syncthreads();
    }
#pragma unroll
    for (int i = 0; i < 8; ++i) ckv[tg * 8 + i][o] = acc[i];
    __syncthreads();

    if (j < 256) {
        int tt = j >> 3, l = j & 7;
        float ss = 0.f;
#pragma unroll
        for (int i = 0; i < 8; ++i) { float v = ckv[tt][l * 8 + i]; ss += v * v; }
        ss += __shfl_xor(ss, 1); ss += __shfl_xor(ss, 2); ss += __shfl_xor(ss, 4);
        float rs = rsqrtf(ss * (1.f / 64.f) + EPSF);
        size_t base = (size_t)(t0 + tt) * 128;
        ushort_t kb[8];
        float clw[8];
#pragma unroll
        for (int i = 0; i < 8; ++i) {
            int o2 = l * 8 + i;
            float cl = ckv[tt][o2] * rs;
            if (isbf) cl = bf2f(f2bf(cl));   // reference: .astype(bf16) before *w
            clw[i] = cl * kvln[o2];
            kb[i] = f2bf(clw[i]);
        }
        uint4 pack;
        pack.x = kb[0] | ((unsigned)kb[1] << 16); pack.y = kb[2] | ((unsigned)kb[3] << 16);
        pack.z = kb[4] | ((unsigned)kb[5] << 16); pack.w = kb[6] | ((unsigned)kb[7] << 16);
        *(uint4*)&Kbf[base + l * 8] = pack;
        int pos = (t0 + tt) & 2047;
        ushort_t r0[4], r1[4];
#pragma unroll
        for (int i = 0; i < 4; ++i) {
            int p = l * 4 + i;
            float2 cssn = tab[pos * 32 + p];
            float e = ckv[tt][64 + 2 * p], od = ckv[tt][64 + 2 * p + 1];
            r0[i] = f2bf(e * cssn.x - od * cssn.y);
            r1[i] = f2bf(od * cssn.x + e * cssn.y);
        }
        uint2 p0, p1;
        p0.x = r0[0] | ((unsigned)r0[1] << 16); p0.y = r0[2] | ((unsigned)r0[3] << 16);
        p1.x = r1[0] | ((unsigned)r1[1] << 16); p1.y = r1[2] | ((unsigned)r1[3] << 16);
        *(uint2*)&Kbf[base + 64 + l * 4] = p0;
        *(uint2*)&Kbf[base + 96 + l * 4] = p1;
#pragma unroll
        for (int i = 0; i < 8; ++i) ckv[tt][l * 8 + i] = clw[i];
    }
    __syncthreads();
    if (j < 256) {   // VT[b][r][t] = c_lat_n[t][r]
        int t = j & 31, rb = (j >> 5) * 8;
        int bb = t0 >> 11, col = (t0 & 2047) + t;
#pragma unroll
        for (int i = 0; i < 8; ++i) {
            int r = rb + i;
            VTbf[((size_t)(bb * 64 + r)) * 2048 + col] = f2bf(ckv[t][r]);
        }
    }
}

// ---------------------------------------------------------------------------
// k2 v3: full-MFMA, barrier-free. 64 tokens/block, 4 waves x 16 tokens.
// Per wave: GEMM1 (src@wq_a^T, K=768, A/B frags from global bf16) -> reg
// RMSNorm -> per-wave LDS -> per head: GEMM2 (K=64) + absorb MFMA (K=32,
// SCALE folded) + table-rope -> q'[16][128] assembled in LDS -> uint4 stores.
// ---------------------------------------------------------------------------
__global__ __launch_bounds__(256) void k2_q(
    const void* __restrict__ src, const float* __restrict__ ws, ushort_t* __restrict__ Qbf)
{
    const int isbf = ((const int*)ws)[OFF_FLAG];
    const ushort_t* srcb = isbf ? (const ushort_t*)src : (const ushort_t*)(ws + OFF_SRCBF);
    const ushort_t* wqab = (const ushort_t*)(ws + OFF_WQAT);   // [64][768]
    const ushort_t* wqbb = (const ushort_t*)(ws + OFF_WQBT);   // [768][64]
    const ushort_t* qabs = (const ushort_t*)(ws + OFF_QAF);    // [8][64][32] *SCALE
    const float2*   tab  = (const float2*)(ws + OFF_ROPE);
    const float*    qln  = ws + OFF_QLN;

    // per-wave LDS: tmpn[16][72] | qn[16][40] | qf[16][136]  (3968 shorts/wave)
    __shared__ __align__(16) ushort_t LDS[4 * 3968];
    int j = threadIdx.x;
    int w = j >> 6, lane = j & 63;
    int tl = lane & 15, qd = lane >> 4;
    ushort_t* tmpn = LDS + w * 3968;
    ushort_t* qn   = tmpn + 1152;
    ushort_t* qf   = qn + 640;
    int t0 = blockIdx.x * 64;
    int tokw = t0 + w * 16;

    // ---- GEMM1: tmp[16][64] = src @ wq_a^T (K=768) ----
    f4_t C1[4];
#pragma unroll
    for (int nt = 0; nt < 4; ++nt) C1[nt] = (f4_t){0.f, 0.f, 0.f, 0.f};
    {
        const ushort_t* ap = srcb + (size_t)(tokw + tl) * 768 + qd * 8;
#pragma unroll 4
        for (int ks = 0; ks < 24; ++ks) {
            bf8_t a = *(const bf8_t*)(ap + ks * 32);
#pragma unroll
            for (int nt = 0; nt < 4; ++nt) {
                bf8_t bfr = *(const bf8_t*)(wqab + (size_t)(nt * 16 + tl) * 768 + ks * 32 + qd * 8);
                C1[nt] = __builtin_amdgcn_mfma_f32_16x16x32_bf16(a, bfr, C1[nt], 0, 0, 0);
            }
        }
    }
    // ---- RMSNorm rows (row m=qd*4+r across 16 tl lanes x 4 nt) ----
    float rsv[4];
#pragma unroll
    for (int r = 0; r < 4; ++r) {
        float s = C1[0][r] * C1[0][r] + C1[1][r] * C1[1][r]
                + C1[2][r] * C1[2][r] + C1[3][r] * C1[3][r];
        s += __shfl_xor(s, 1); s += __shfl_xor(s, 2);
        s += __shfl_xor(s, 4); s += __shfl_xor(s, 8);
        rsv[r] = rsqrtf(s * (1.f / 64.f) + EPSF);
    }
    float qlnv[4];
#pragma unroll
    for (int nt = 0; nt < 4; ++nt) qlnv[nt] = qln[nt * 16 + tl];
#pragma unroll
    for (int nt = 0; nt < 4; ++nt)
#pragma unroll
        for (int r = 0; r < 4; ++r) {
            float v = C1[nt][r] * rsv[r];
            if (isbf) v = bf2f(f2bf(v));      // .astype(bf16) before *w
            tmpn[(qd * 4 + r) * 72 + nt * 16 + tl] = f2bf(v * qlnv[nt]);
        }
    // A2 frags (head-independent): A[m=tl][k=ks*32+qd*8]
    bf8_t A2[2];
#pragma unroll
    for (int ks = 0; ks < 2; ++ks) A2[ks] = *(const bf8_t*)(tmpn + tl * 72 + ks * 32 + qd * 8);

    // ---- rope cos/sin preload (head-independent), scaled by SCALE ----
    float csv[4][4], snv[4][4];
#pragma unroll
    for (int nt2 = 0; nt2 < 4; ++nt2) {
        int p = (nt2 * 16 + tl) >> 1;
#pragma unroll
        for (int r = 0; r < 4; ++r) {
            int pos = (tokw + qd * 4 + r) & 2047;
            float2 t = tab[pos * 32 + p];
            csv[nt2][r] = t.x * SCALE;
            snv[nt2][r] = t.y * SCALE;
        }
    }
    const bool evn = !(tl & 1);
    int bb = tokw >> 11, pos0 = tokw & 2047;

    // ---- per head ----
    for (int h = 0; h < 8; ++h) {
        f4_t C2[6];
#pragma unroll
        for (int nt = 0; nt < 6; ++nt) C2[nt] = (f4_t){0.f, 0.f, 0.f, 0.f};
#pragma unroll
        for (int nt = 0; nt < 6; ++nt)
#pragma unroll
            for (int ks = 0; ks < 2; ++ks) {
                bf8_t bfr = *(const bf8_t*)(wqbb + (size_t)(h * 96 + nt * 16 + tl) * 64 + ks * 32 + qd * 8);
                C2[nt] = __builtin_amdgcn_mfma_f32_16x16x32_bf16(A2[ks], bfr, C2[nt], 0, 0, 0);
            }
        // q_nope (cols 0..31) -> per-wave LDS (A-layout source)
#pragma unroll
        for (int nt = 0; nt < 2; ++nt)
#pragma unroll
            for (int r = 0; r < 4; ++r)
                qn[(qd * 4 + r) * 40 + nt * 16 + tl] = f2bf(C2[nt][r]);
        bf8_t an = *(const bf8_t*)(qn + tl * 40 + qd * 8);
        // absorb: q_lat[16][64] = q_nope @ q_absorbT_h (K=32, pre-scaled)
        f4_t C3[4];
#pragma unroll
        for (int nt = 0; nt < 4; ++nt) C3[nt] = (f4_t){0.f, 0.f, 0.f, 0.f};
#pragma unroll
        for (int nt = 0; nt < 4; ++nt) {
            bf8_t bfr = *(const bf8_t*)(qabs + (size_t)h * 2048 + (nt * 16 + tl) * 32 + qd * 8);
            C3[nt] = __builtin_amdgcn_mfma_f32_16x16x32_bf16(an, bfr, C3[nt], 0, 0, 0);
        }
        // scatter q_lat -> qf cols 0..63
#pragma unroll
        for (int nt = 0; nt < 4; ++nt)
#pragma unroll
            for (int r = 0; r < 4; ++r)
                qf[(qd * 4 + r) * 136 + nt * 16 + tl] = f2bf(C3[nt][r]);
        // rope on q_pe (C2[2..5]) -> qf cols 64..127
#pragma unroll
        for (int nt2 = 0; nt2 < 4; ++nt2) {
            int p = (nt2 * 16 + tl) >> 1;
            int outc = evn ? (64 + p) : (96 + p);
#pragma unroll
            for (int r = 0; r < 4; ++r) {
                float val = C2[nt2 + 2][r];
                float part = __shfl_xor(val, 1);
                float res = evn ? (val * csv[nt2][r] - part * snv[nt2][r])
                                : (val * csv[nt2][r] + part * snv[nt2][r]);
                qf[(qd * 4 + r) * 136 + outc] = f2bf(res);
            }
        }
        // packed store: q'[16][128] -> Qbf[b][h][pos][128]
        size_t qb = ((size_t)(bb * 8 + h) * 2048 + pos0) * 128;
#pragma unroll
        for (int i = 0; i < 4; ++i) {
            int idx = i * 64 + lane;
            int row = idx >> 4, c = idx & 15;
            uint4 v = *(const uint4*)(qf + row * 136 + c * 8);
            *(uint4*)(Qbf + qb + (size_t)row * 128 + c * 8) = v;
        }
    }
}

// ---------------------------------------------------------------------------
// k3: MFMA flash attention (round 5). grid (16,8,4), 8 waves x 16 q.
// ---------------------------------------------------------------------------
__global__ __launch_bounds__(512, 4) void k3_attn(
    const ushort_t* __restrict__ Qbf, const ushort_t* __restrict__ Kbf,
    const ushort_t* __restrict__ VTbf, const float* __restrict__ oaT,
    ushort_t* __restrict__ ctxb)
{
    __shared__ __align__(16) ushort_t LDS[22528];
    ushort_t* Kt = LDS;                    // [64][136]
    ushort_t* Vt = LDS + 8704;             // [64][72]
    ushort_t* Pw = LDS + 13312;            // [8][16][72]
    int j = threadIdx.x;
    int b = blockIdx.z, h = blockIdx.y, q0g = blockIdx.x * 128;
    int w = j >> 6, lane = j & 63;
    int tl = lane & 15, qd = lane >> 4;
    ushort_t* Pme = Pw + w * 1152;
    int qw = q0g + w * 16;

    bf8_t qfrag[4];
    {
        const ushort_t* qp = Qbf + ((size_t)((b * 8 + h) * 2048) + qw + tl) * 128 + qd * 8;
#pragma unroll
        for (int ks = 0; ks < 4; ++ks) qfrag[ks] = *(const bf8_t*)(qp + ks * 32);
    }
    f4_t Oacc[4];
#pragma unroll
    for (int nt = 0; nt < 4; ++nt) Oacc[nt] = (f4_t){0.f, 0.f, 0.f, 0.f};
    float m_own = -1e30f, l_own = 0.f;

    const size_t kbase = (size_t)b * 2048 * 128;
    const size_t vbase = (size_t)b * 64 * 2048;

    for (int it = 0; it < 32; ++it) {
        __syncthreads();
        {
            int r = j >> 3, c0 = (j & 7) * 16;
            const uint4* gp = (const uint4*)(Kbf + kbase + (size_t)(it * 64 + r) * 128 + c0);
            uint4 a0 = gp[0], a1 = gp[1];
            uint4* dp = (uint4*)(Kt + r * 136 + c0);
            dp[0] = a0; dp[1] = a1;
        }
        {
            int d = j >> 3, c0 = (j & 7) * 8;
            uint4 v = *(const uint4*)(VTbf + vbase + (size_t)d * 2048 + it * 64 + c0);
            *(uint4*)(Vt + d * 72 + c0) = v;
        }
        __syncthreads();
        f4_t S[4];
#pragma unroll
        for (int nt = 0; nt < 4; ++nt) {
            f4_t c = (f4_t){0.f, 0.f, 0.f, 0.f};
#pragma unroll
            for (int ks = 0; ks < 4; ++ks) {
                bf8_t kf = *(const bf8_t*)(Kt + (nt * 16 + tl) * 136 + ks * 32 + qd * 8);
                c = __builtin_amdgcn_mfma_f32_16x16x32_bf16(kf, qfrag[ks], c, 0, 0, 0);
            }
            S[nt] = c;
        }
        float mt;
        {
            float a0 = fmaxf(fmaxf(S[0][0], S[0][1]), fmaxf(S[0][2], S[0][3]));
            float a1 = fmaxf(fmaxf(S[1][0], S[1][1]), fmaxf(S[1][2], S[1][3]));
            float a2 = fmaxf(fmaxf(S[2][0], S[2][1]), fmaxf(S[2][2], S[2][3]));
            float a3 = fmaxf(fmaxf(S[3][0], S[3][1]), fmaxf(S[3][2], S[3][3]));
            mt = fmaxf(fmaxf(a0, a1), fmaxf(a2, a3));
        }
        mt = fmaxf(mt, __shfl_xor(mt, 16));
        mt = fmaxf(mt, __shfl_xor(mt, 32));
        float mn = fmaxf(m_own, mt);
        float al = __expf(m_own - mn);
        float rsum = 0.f;
#pragma unroll
        for (int nt = 0; nt < 4; ++nt)
#pragma unroll
            for (int r = 0; r < 4; ++r) {
                float p = __expf(S[nt][r] - mn);
                S[nt][r] = p; rsum += p;
            }
        rsum += __shfl_xor(rsum, 16);
        rsum += __shfl_xor(rsum, 32);
        l_own = l_own * al + rsum;
        m_own = mn;
#pragma unroll
        for (int nt = 0; nt < 4; ++nt) {
            uint2 pk;
            pk.x = f2bf(S[nt][0]) | ((unsigned)f2bf(S[nt][1]) << 16);
            pk.y = f2bf(S[nt][2]) | ((unsigned)f2bf(S[nt][3]) << 16);
            *(uint2*)(Pme + tl * 72 + nt * 16 + qd * 4) = pk;
        }
#pragma unroll
        for (int r = 0; r < 4; ++r) {
            float alr = __shfl(al, (lane & 48) + qd * 4 + r);
#pragma unroll
            for (int nt = 0; nt < 4; ++nt) Oacc[nt][r] *= alr;
        }
        bf8_t pf[2];
#pragma unroll
        for (int ks = 0; ks < 2; ++ks) pf[ks] = *(const bf8_t*)(Pme + tl * 72 + ks * 32 + qd * 8);
#pragma unroll
        for (int nt = 0; nt < 4; ++nt)
#pragma unroll
            for (int ks = 0; ks < 2; ++ks) {
                bf8_t vf = *(const bf8_t*)(Vt + (nt * 16 + tl) * 72 + ks * 32 + qd * 8);
                Oacc[nt] = __builtin_amdgcn_mfma_f32_16x16x32_bf16(pf[ks], vf, Oacc[nt], 0, 0, 0);
            }
    }
    {
        float linv[4];
#pragma unroll
        for (int r = 0; r < 4; ++r) {
            float lq = __shfl(l_own, (lane & 48) + qd * 4 + r);
            linv[r] = 1.f / lq;
        }
#pragma unroll
        for (int nt = 0; nt < 4; ++nt)
#pragma unroll
            for (int r = 0; r < 4; ++r)
                Pme[(qd * 4 + r) * 72 + nt * 16 + tl] = f2bf(Oacc[nt][r] * linv[r]);
    }
    __syncthreads();
    ushort_t* OA = LDS;  // [96][72]
    for (int e = j; e < 96 * 64; e += 512) {
        int v = e >> 6, r = e & 63;
        OA[v * 72 + r] = f2bf(oaT[h * 6144 + r * 96 + v]);
    }
    __syncthreads();
    {
        bf8_t of[2];
#pragma unroll
        for (int ks = 0; ks < 2; ++ks) of[ks] = *(const bf8_t*)(Pme + tl * 72 + ks * 32 + qd * 8);
#pragma unroll
        for (int nt = 0; nt < 6; ++nt) {
            f4_t c = (f4_t){0.f, 0.f, 0.f, 0.f};
#pragma unroll
            for (int ks = 0; ks < 2; ++ks) {
                bf8_t af = *(const bf8_t*)(OA + (nt * 16 + tl) * 72 + ks * 32 + qd * 8);
                c = __builtin_amdgcn_mfma_f32_16x16x32_bf16(of[ks], af, c, 0, 0, 0);
            }
#pragma unroll
            for (int r = 0; r < 4; ++r) {
                size_t tok = (size_t)(b * 2048 + qw + qd * 4 + r);
                ctxb[tok * 768 + h * 96 + nt * 16 + tl] = f2bf(c[r]);
            }
        }
    }
}

// ---------------------------------------------------------------------------
// k5: MFMA wo-GEMM + fused residual + RMSNorm (round 4).
// ---------------------------------------------------------------------------
__global__ __launch_bounds__(256, 1) void k5_out(
    const void* __restrict__ src, const float* __restrict__ ws,
    const ushort_t* __restrict__ ctxb, void* __restrict__ out)
{
    const ushort_t* woB = (const ushort_t*)(ws + OFF_WOT);
    const float* nw = ws + OFF_NW;
    const int isbf = ((const int*)ws)[OFF_FLAG];
    __shared__ __align__(16) ushort_t ylds[32 * 776];
    int j = threadIdx.x;
    int t0 = blockIdx.x * 32;
    int w = j >> 6, lane = j & 63;
    int tl = lane & 15, qd = lane >> 4;
    int n0 = w * 192;

    {
        for (int e = j; e < 32 * 96; e += 256) {
            int row = e / 96, c16 = e - row * 96;
            uint4 v = *(const uint4*)(ctxb + (size_t)(t0 + row) * 768 + c16 * 8);
            *(uint4*)(ylds + row * 776 + c16 * 8) = v;
        }
    }
    __syncthreads();

    f4_t acc[2][12];
#pragma unroll
    for (int mt = 0; mt < 2; ++mt)
#pragma unroll
        for (int nt = 0; nt < 12; ++nt) acc[mt][nt] = (f4_t){0.f, 0.f, 0.f, 0.f};

#pragma unroll 2
    for (int ks = 0; ks < 24; ++ks) {
        bf8_t a0 = *(const bf8_t*)(ylds + tl * 776 + ks * 32 + qd * 8);
        bf8_t a1 = *(const bf8_t*)(ylds + (16 + tl) * 776 + ks * 32 + qd * 8);
#pragma unroll
        for (int nt = 0; nt < 12; ++nt) {
            bf8_t bfr = *(const bf8_t*)(woB + (size_t)(n0 + nt * 16 + tl) * 768 + ks * 32 + qd * 8);
            acc[0][nt] = __builtin_amdgcn_mfma_f32_16x16x32_bf16(a0, bfr, acc[0][nt], 0, 0, 0);
            acc[1][nt] = __builtin_amdgcn_mfma_f32_16x16x32_bf16(a1, bfr, acc[1][nt], 0, 0, 0);
        }
    }
    __syncthreads();

    {
#pragma unroll
        for (int mt = 0; mt < 2; ++mt)
#pragma unroll
            for (int nt = 0; nt < 12; ++nt)
#pragma unroll
                for (int r = 0; r < 4; ++r) {
                    int trow = mt * 16 + qd * 4 + r;
                    int col = n0 + nt * 16 + tl;
                    float yv = acc[mt][nt][r] + ldin(src, (size_t)(t0 + trow) * 768 + col, isbf);
                    ylds[trow * 776 + col] = f2bf(yv);
                }
    }
    __syncthreads();
    {
        int tt = j >> 3, sub = j & 7;
        const ushort_t* yp = ylds + tt * 776 + sub * 96;
        float ss = 0.f;
#pragma unroll
        for (int c = 0; c < 96; ++c) { float v = bf2f(yp[c]); ss += v * v; }
        ss += __shfl_xor(ss, 1); ss += __shfl_xor(ss, 2); ss += __shfl_xor(ss, 4);
        float rs = rsqrtf(ss * (1.f / 768.f) + EPSF);
        size_t base = (size_t)(t0 + tt) * 768 + sub * 96;
        if (isbf) {
            ushort_t* op = (ushort_t*)out + base;
#pragma unroll
            for (int c8 = 0; c8 < 12; ++c8) {
                ushort_t tmp[8];
#pragma unroll
                for (int c = 0; c < 8; ++c) {
                    float yv = bf2f(yp[c8 * 8 + c]);
                    float hv = bf2f(f2bf(yv * rs));
                    tmp[c] = f2bf(hv * nw[sub * 96 + c8 * 8 + c]);
                }
                *(uint4*)(op + c8 * 8) = *(const uint4*)tmp;
            }
        } else {
            float* op = (float*)out + base;
#pragma unroll
            for (int c = 0; c < 96; ++c) {
                float yv = bf2f(yp[c]);
                op[c] = yv * rs * nw[sub * 96 + c];
            }
        }
    }
}

// ---------------------------------------------------------------------------
extern "C" void kernel_launch(void* const* d_in, const int* in_sizes, int n_in,
                              void* d_out, int out_size, void* d_ws, size_t ws_size,
                              hipStream_t stream)
{
    const void* src   = d_in[0];
    const void* wq_a  = d_in[1];
    const void* q_ln  = d_in[2];
    const void* wq_b  = d_in[3];
    const void* wkv_a = d_in[4];
    const void* kv_ln = d_in[5];
    const void* wkv_b = d_in[6];
    const void* wo    = d_in[7];
    const void* nw    = d_in[8];
    float* ws = (float*)d_ws;
    ushort_t* Kbf   = (ushort_t*)(ws + OFF_KBF);
    ushort_t* VTbf  = (ushort_t*)(ws + OFF_VTB);
    ushort_t* Qbf   = (ushort_t*)(ws + OFF_QBF);
    ushort_t* ctxb  = (ushort_t*)(ws + OFF_CTXF);
    ushort_t* srcbf = (ushort_t*)(ws + OFF_SRCBF);

    det_k<<<dim3(1), dim3(1), 0, stream>>>((const unsigned int*)nw, (int*)ws + OFF_FLAG);
    prep_k<<<dim3(2304, 8), dim3(256), 0, stream>>>(wq_a, q_ln, wq_b, wkv_a, kv_ln, wkv_b, wo, nw, ws);
    k1_ckv<<<dim3(TOK / 32), dim3(512), 0, stream>>>(src, ws, Kbf, VTbf, srcbf);
    k2_q<<<dim3(TOK / 64), dim3(256), 0, stream>>>(src, ws, Qbf);
    k3_attn<<<dim3(16, 8, 4), dim3(512), 0, stream>>>(Qbf, Kbf, VTbf, ws + OFF_OAT, ctxb);
    k5_out<<<dim3(TOK / 32), dim3(256), 0, stream>>>(src, ws, ctxb, d_out);
}